// Round 8
// baseline (1092.782 us; speedup 1.0000x reference)
//
#include <hip/hip_runtime.h>
#include <math.h>

#define NN 100000
#define NE 1600000
constexpr int IN_DIM = 128;
constexpr int ED_DIM = 16;
constexpr int D = 16;
constexpr int CD = 8;
constexpr int C = 10;

constexpr int NB   = 256;                 // dst buckets
constexpr int NR   = 391;                 // nodes per bucket
constexpr int NBT  = NB * NR;             // 100096
constexpr int NBLK = 256;                 // blocks for hist/scatter
constexpr int EPB  = (NE + NBLK - 1) / NBLK;  // 6250
constexpr int AGG_BLOCKS = (NN * 16 + 255) / 256;  // 6250: 16 lanes per node

__device__ __forceinline__ float leaky(float v) { return v >= 0.f ? v : 0.01f * v; }

// ---------- edge encoder helper ----------
__device__ __forceinline__ void edge_encode(
    const float* __restrict__ earaw, int e,
    const float* __restrict__ ew1, const float* __restrict__ eb1,
    const float* __restrict__ ew2, const float* __restrict__ eb2,
    float* __restrict__ ea /*16*/) {
    float r[ED_DIM];
    const float4* er = reinterpret_cast<const float4*>(earaw + (size_t)e * ED_DIM);
#pragma unroll
    for (int q = 0; q < 4; ++q) {
        float4 v = er[q];
        r[4 * q] = v.x; r[4 * q + 1] = v.y; r[4 * q + 2] = v.z; r[4 * q + 3] = v.w;
    }
    float t[D];
#pragma unroll
    for (int j = 0; j < D; ++j) t[j] = eb1[j];
#pragma unroll
    for (int k = 0; k < ED_DIM; ++k)
#pragma unroll
        for (int j = 0; j < D; ++j) t[j] += r[k] * ew1[k * D + j];
#pragma unroll
    for (int j = 0; j < D; ++j) t[j] = leaky(t[j]);
#pragma unroll
    for (int j = 0; j < D; ++j) ea[j] = eb2[j];
#pragma unroll
    for (int k = 0; k < D; ++k)
#pragma unroll
        for (int j = 0; j < D; ++j) ea[j] += t[k] * ew2[k * D + j];
}

__device__ __forceinline__ void mlp1(
    float* __restrict__ a /*32 in, clobbered*/,
    const float* __restrict__ w1, const float* __restrict__ b1,
    const float* __restrict__ w2, const float* __restrict__ b2,
    const float* __restrict__ w3, const float* __restrict__ b3,
    float* __restrict__ o /*8*/) {
    float bv[32];
#pragma unroll
    for (int j = 0; j < 32; ++j) bv[j] = b1[j];
#pragma unroll
    for (int k = 0; k < 32; ++k)
#pragma unroll
        for (int j = 0; j < 32; ++j) bv[j] += a[k] * w1[k * 32 + j];
#pragma unroll
    for (int j = 0; j < 32; ++j) bv[j] = leaky(bv[j]);
#pragma unroll
    for (int j = 0; j < 32; ++j) a[j] = b2[j];
#pragma unroll
    for (int k = 0; k < 32; ++k)
#pragma unroll
        for (int j = 0; j < 32; ++j) a[j] += bv[k] * w2[k * 32 + j];
#pragma unroll
    for (int j = 0; j < 32; ++j) a[j] = leaky(a[j]);
#pragma unroll
    for (int j = 0; j < CD; ++j) o[j] = b3[j];
#pragma unroll
    for (int k = 0; k < 32; ++k)
#pragma unroll
        for (int j = 0; j < CD; ++j) o[j] += a[k] * w3[k * CD + j];
}

__device__ __forceinline__ void mlp2(
    float* __restrict__ a /*24 in, clobbered*/,
    const float* __restrict__ w1, const float* __restrict__ b1,
    const float* __restrict__ w2, const float* __restrict__ b2,
    const float* __restrict__ w3, const float* __restrict__ b3,
    float* __restrict__ o /*10*/) {
    constexpr int M = CD + D;  // 24
    float bv[M];
#pragma unroll
    for (int j = 0; j < M; ++j) bv[j] = b1[j];
#pragma unroll
    for (int k = 0; k < M; ++k)
#pragma unroll
        for (int j = 0; j < M; ++j) bv[j] += a[k] * w1[k * M + j];
#pragma unroll
    for (int j = 0; j < M; ++j) bv[j] = leaky(bv[j]);
#pragma unroll
    for (int j = 0; j < M; ++j) a[j] = b2[j];
#pragma unroll
    for (int k = 0; k < M; ++k)
#pragma unroll
        for (int j = 0; j < M; ++j) a[j] += bv[k] * w2[k * M + j];
#pragma unroll
    for (int j = 0; j < M; ++j) a[j] = leaky(a[j]);
#pragma unroll
    for (int j = 0; j < C; ++j) o[j] = b3[j];
#pragma unroll
    for (int k = 0; k < M; ++k)
#pragma unroll
        for (int j = 0; j < C; ++j) o[j] += a[k] * w3[k * C + j];
}

// ---------------- zero region (fallback only) ----------------
__global__ __launch_bounds__(256) void k_zero(float* __restrict__ p, int n) {
    int i = blockIdx.x * 256 + threadIdx.x;
    if (i < n) p[i] = 0.f;
}

// ---------------- node encoder (sorted paths): writes hW1[32] and hroot[8] per node ----------------
__global__ __launch_bounds__(256) void k_node_enc2(
    const float* __restrict__ x, const float* __restrict__ twin,
    const float* __restrict__ w1, const float* __restrict__ b1,
    const float* __restrict__ w2, const float* __restrict__ b2,
    const float* __restrict__ tww, const float* __restrict__ twb,
    const float* __restrict__ nn1w1, const float* __restrict__ root1,
    float* __restrict__ hW1, float* __restrict__ hroot) {
    int i = blockIdx.x * 256 + threadIdx.x;
    if (i >= NN) return;
    float acc[D];
#pragma unroll
    for (int j = 0; j < D; ++j) acc[j] = b1[j];
    const float4* xr = reinterpret_cast<const float4*>(x + (size_t)i * IN_DIM);
#pragma unroll 8
    for (int k4 = 0; k4 < IN_DIM / 4; ++k4) {
        float4 xv = xr[k4];
        const float* wr = w1 + (k4 * 4) * D;
#pragma unroll
        for (int j = 0; j < D; ++j) acc[j] += xv.x * wr[j];
#pragma unroll
        for (int j = 0; j < D; ++j) acc[j] += xv.y * wr[D + j];
#pragma unroll
        for (int j = 0; j < D; ++j) acc[j] += xv.z * wr[2 * D + j];
#pragma unroll
        for (int j = 0; j < D; ++j) acc[j] += xv.w * wr[3 * D + j];
    }
    float t[D];
#pragma unroll
    for (int j = 0; j < D; ++j) t[j] = leaky(acc[j]);
    float h2[D];
#pragma unroll
    for (int j = 0; j < D; ++j) h2[j] = b2[j];
#pragma unroll
    for (int k = 0; k < D; ++k)
#pragma unroll
        for (int j = 0; j < D; ++j) h2[j] += t[k] * w2[k * D + j];
    float twv = twin[i];
#pragma unroll
    for (int j = 0; j < D; ++j) h2[j] *= (twv * tww[j] + twb[j]);
    float hw[32];
#pragma unroll
    for (int j = 0; j < 32; ++j) hw[j] = 0.f;
#pragma unroll
    for (int k = 0; k < D; ++k)
#pragma unroll
        for (int j = 0; j < 32; ++j) hw[j] += h2[k] * nn1w1[k * 32 + j];
    float4* hwo = reinterpret_cast<float4*>(hW1 + (size_t)i * 32);
#pragma unroll
    for (int q = 0; q < 8; ++q)
        hwo[q] = make_float4(hw[4 * q], hw[4 * q + 1], hw[4 * q + 2], hw[4 * q + 3]);
    float hr[CD];
#pragma unroll
    for (int j = 0; j < CD; ++j) hr[j] = 0.f;
#pragma unroll
    for (int k = 0; k < D; ++k)
#pragma unroll
        for (int j = 0; j < CD; ++j) hr[j] += h2[k] * root1[k * CD + j];
    float4* hro = reinterpret_cast<float4*>(hroot + (size_t)i * CD);
    hro[0] = make_float4(hr[0], hr[1], hr[2], hr[3]);
    hro[1] = make_float4(hr[4], hr[5], hr[6], hr[7]);
}

// ---------------- node encoder (atomic fallback): writes h[16] ----------------
__global__ __launch_bounds__(256) void k_node_enc(
    const float* __restrict__ x, const float* __restrict__ twin,
    const float* __restrict__ w1, const float* __restrict__ b1,
    const float* __restrict__ w2, const float* __restrict__ b2,
    const float* __restrict__ tww, const float* __restrict__ twb,
    float* __restrict__ hout) {
    int i = blockIdx.x * 256 + threadIdx.x;
    if (i >= NN) return;
    float acc[D];
#pragma unroll
    for (int j = 0; j < D; ++j) acc[j] = b1[j];
    const float4* xr = reinterpret_cast<const float4*>(x + (size_t)i * IN_DIM);
#pragma unroll 8
    for (int k4 = 0; k4 < IN_DIM / 4; ++k4) {
        float4 xv = xr[k4];
        const float* wr = w1 + (k4 * 4) * D;
#pragma unroll
        for (int j = 0; j < D; ++j) acc[j] += xv.x * wr[j];
#pragma unroll
        for (int j = 0; j < D; ++j) acc[j] += xv.y * wr[D + j];
#pragma unroll
        for (int j = 0; j < D; ++j) acc[j] += xv.z * wr[2 * D + j];
#pragma unroll
        for (int j = 0; j < D; ++j) acc[j] += xv.w * wr[3 * D + j];
    }
    float t[D];
#pragma unroll
    for (int j = 0; j < D; ++j) t[j] = leaky(acc[j]);
    float h2[D];
#pragma unroll
    for (int j = 0; j < D; ++j) h2[j] = b2[j];
#pragma unroll
    for (int k = 0; k < D; ++k)
#pragma unroll
        for (int j = 0; j < D; ++j) h2[j] += t[k] * w2[k * D + j];
    float twv = twin[i];
#pragma unroll
    for (int j = 0; j < D; ++j) h2[j] *= (twv * tww[j] + twb[j]);
    float4* ho = reinterpret_cast<float4*>(hout + (size_t)i * D);
#pragma unroll
    for (int q = 0; q < 4; ++q)
        ho[q] = make_float4(h2[4 * q], h2[4 * q + 1], h2[4 * q + 2], h2[4 * q + 3]);
}

// ---------------- sort level 1 ----------------
__global__ __launch_bounds__(256) void k_hist(const int* __restrict__ ei,
                                              unsigned* __restrict__ histp) {
    __shared__ unsigned hist[NB];
    int tid = threadIdx.x, blk = blockIdx.x;
    hist[tid] = 0;
    __syncthreads();
    int lo = blk * EPB, hi = min(lo + EPB, NE);
    for (int t = lo + tid; t < hi; t += 256) {
        int dst = ei[NE + t];
        atomicAdd(&hist[dst / NR], 1u);
    }
    __syncthreads();
    histp[tid * NBLK + blk] = hist[tid];  // [bin][blk]
}

__global__ __launch_bounds__(256) void k_scanA(const unsigned* __restrict__ histp,
                                               unsigned* __restrict__ offp,
                                               unsigned* __restrict__ total) {
    __shared__ unsigned buf[256];
    int j = blockIdx.x, t = threadIdx.x;
    unsigned v = histp[j * NBLK + t];
    buf[t] = v;
    __syncthreads();
    for (int d = 1; d < 256; d <<= 1) {
        unsigned add = (t >= d) ? buf[t - d] : 0u;
        __syncthreads();
        buf[t] += add;
        __syncthreads();
    }
    offp[j * NBLK + t] = buf[t] - v;
    if (t == 255) total[j] = buf[255];
}

__global__ __launch_bounds__(256) void k_scanB(const unsigned* __restrict__ total,
                                               unsigned* __restrict__ bstart,
                                               float* __restrict__ bn) {
    __shared__ unsigned buf[256];
    int t = threadIdx.x;
    unsigned v = total[t];
    buf[t] = v;
    __syncthreads();
    for (int d = 1; d < 256; d <<= 1) {
        unsigned add = (t >= d) ? buf[t - d] : 0u;
        __syncthreads();
        buf[t] += add;
        __syncthreads();
    }
    bstart[t] = buf[t] - v;
    if (t == 255) bstart[256] = buf[255];
    if (t < 32) bn[t] = 0.f;
}

__global__ __launch_bounds__(256) void k_scatter(const int* __restrict__ ei,
                                                 const unsigned* __restrict__ offp,
                                                 const unsigned* __restrict__ bstart,
                                                 int* __restrict__ pe, int* __restrict__ ps,
                                                 int* __restrict__ pd) {
    __shared__ unsigned cur[NB];
    int tid = threadIdx.x, blk = blockIdx.x;
    cur[tid] = bstart[tid] + offp[tid * NBLK + blk];
    __syncthreads();
    int lo = blk * EPB, hi = min(lo + EPB, NE);
    for (int t = lo + tid; t < hi; t += 256) {
        int dst = ei[NE + t];
        int src = ei[t];
        int bin = dst / NR;
        unsigned pos = atomicAdd(&cur[bin], 1u);
        pe[pos] = t; ps[pos] = src; pd[pos] = dst;
    }
}

// ---------------- sort level 2 ----------------
__global__ __launch_bounds__(256) void k_sort2(
    const int* __restrict__ pe, const int* __restrict__ ps, const int* __restrict__ pd,
    const unsigned* __restrict__ bstart,
    int* __restrict__ pe2, int* __restrict__ ps2, unsigned* __restrict__ nptr) {
    __shared__ unsigned cnt[512];
    __shared__ unsigned cur[NR];
    int b = blockIdx.x, tid = threadIdx.x;
    int s0 = (int)bstart[b], s1 = (int)bstart[b + 1];
    int base = b * NR;
    cnt[tid] = 0; cnt[tid + 256] = 0;
    __syncthreads();
    for (int t = s0 + tid; t < s1; t += 256)
        atomicAdd(&cnt[pd[t] - base], 1u);
    __syncthreads();
    for (int d = 1; d < 512; d <<= 1) {
        unsigned v0 = (tid >= d) ? cnt[tid - d] : 0u;
        unsigned v1 = (tid + 256 >= (unsigned)d) ? cnt[tid + 256 - d] : 0u;
        __syncthreads();
        cnt[tid] += v0; cnt[tid + 256] += v1;
        __syncthreads();
    }
    for (int r = tid; r < NR; r += 256) {
        unsigned off = (r == 0) ? 0u : cnt[r - 1];
        nptr[base + r] = s0 + off;
        cur[r] = s0 + off;
    }
    if (b == NB - 1 && tid == 0) nptr[NBT] = (unsigned)s1;
    __syncthreads();
    for (int t = s0 + tid; t < s1; t += 256) {
        int r = pd[t] - base;
        unsigned pos = atomicAdd(&cur[r], 1u);
        pe2[pos] = pe[t]; ps2[pos] = ps[t];
    }
}

// ---------------- conv1 messages (writes sorted ea for conv2 reuse) ----------------
__global__ __launch_bounds__(256, 4) void k_conv1mw(
    const float* __restrict__ earaw, const int* __restrict__ pe2, const int* __restrict__ ps2,
    const float* __restrict__ hW1,
    const float* __restrict__ ew1, const float* __restrict__ eb1,
    const float* __restrict__ ew2, const float* __restrict__ eb2,
    const float* __restrict__ w1, const float* __restrict__ b1,
    const float* __restrict__ w2, const float* __restrict__ b2,
    const float* __restrict__ w3, const float* __restrict__ b3,
    float* __restrict__ msgs, float* __restrict__ eaS) {
    int t = blockIdx.x * 256 + threadIdx.x;
    if (t >= NE) return;
    int e = pe2[t], src = ps2[t];
    float ea[D];
    edge_encode(earaw, e, ew1, eb1, ew2, eb2, ea);
    float4* eo = reinterpret_cast<float4*>(eaS + (size_t)t * 16);
#pragma unroll
    for (int q = 0; q < 4; ++q)
        eo[q] = make_float4(ea[4 * q], ea[4 * q + 1], ea[4 * q + 2], ea[4 * q + 3]);
    float a[32];
    const float4* hg = reinterpret_cast<const float4*>(hW1 + (size_t)src * 32);
#pragma unroll
    for (int q = 0; q < 8; ++q) {
        float4 v = hg[q];
        a[4 * q] = v.x; a[4 * q + 1] = v.y; a[4 * q + 2] = v.z; a[4 * q + 3] = v.w;
    }
#pragma unroll
    for (int j = 0; j < 32; ++j) a[j] += b1[j];
#pragma unroll
    for (int k = 0; k < D; ++k)
#pragma unroll
        for (int j = 0; j < 32; ++j) a[j] += ea[k] * w1[(16 + k) * 32 + j];
#pragma unroll
    for (int j = 0; j < 32; ++j) a[j] = leaky(a[j]);
    float bv[32];
#pragma unroll
    for (int j = 0; j < 32; ++j) bv[j] = b2[j];
#pragma unroll
    for (int k = 0; k < 32; ++k)
#pragma unroll
        for (int j = 0; j < 32; ++j) bv[j] += a[k] * w2[k * 32 + j];
#pragma unroll
    for (int j = 0; j < 32; ++j) bv[j] = leaky(bv[j]);
    float o[CD];
#pragma unroll
    for (int j = 0; j < CD; ++j) o[j] = b3[j];
#pragma unroll
    for (int k = 0; k < 32; ++k)
#pragma unroll
        for (int j = 0; j < CD; ++j) o[j] += bv[k] * w3[k * CD + j];
    float4* mp = reinterpret_cast<float4*>(msgs + (size_t)t * CD);
    mp[0] = make_float4(o[0], o[1], o[2], o[3]);
    mp[1] = make_float4(o[4], o[5], o[6], o[7]);
}

// ---------------- conv1 messages (mid fallback, no eaS) ----------------
__global__ __launch_bounds__(256) void k_conv1m(
    const float* __restrict__ earaw, const int* __restrict__ pe2, const int* __restrict__ ps2,
    const float* __restrict__ hW1,
    const float* __restrict__ ew1, const float* __restrict__ eb1,
    const float* __restrict__ ew2, const float* __restrict__ eb2,
    const float* __restrict__ w1, const float* __restrict__ b1,
    const float* __restrict__ w2, const float* __restrict__ b2,
    const float* __restrict__ w3, const float* __restrict__ b3,
    float* __restrict__ msgs) {
    int t = blockIdx.x * 256 + threadIdx.x;
    if (t >= NE) return;
    int e = pe2[t], src = ps2[t];
    float ea[D];
    edge_encode(earaw, e, ew1, eb1, ew2, eb2, ea);
    float a[32];
    const float4* hg = reinterpret_cast<const float4*>(hW1 + (size_t)src * 32);
#pragma unroll
    for (int q = 0; q < 8; ++q) {
        float4 v = hg[q];
        a[4 * q] = v.x; a[4 * q + 1] = v.y; a[4 * q + 2] = v.z; a[4 * q + 3] = v.w;
    }
#pragma unroll
    for (int j = 0; j < 32; ++j) a[j] += b1[j];
#pragma unroll
    for (int k = 0; k < D; ++k)
#pragma unroll
        for (int j = 0; j < 32; ++j) a[j] += ea[k] * w1[(16 + k) * 32 + j];
#pragma unroll
    for (int j = 0; j < 32; ++j) a[j] = leaky(a[j]);
    float bv[32];
#pragma unroll
    for (int j = 0; j < 32; ++j) bv[j] = b2[j];
#pragma unroll
    for (int k = 0; k < 32; ++k)
#pragma unroll
        for (int j = 0; j < 32; ++j) bv[j] += a[k] * w2[k * 32 + j];
#pragma unroll
    for (int j = 0; j < 32; ++j) bv[j] = leaky(bv[j]);
    float o[CD];
#pragma unroll
    for (int j = 0; j < CD; ++j) o[j] = b3[j];
#pragma unroll
    for (int k = 0; k < 32; ++k)
#pragma unroll
        for (int j = 0; j < CD; ++j) o[j] += bv[k] * w3[k * CD + j];
    float4* mp = reinterpret_cast<float4*>(msgs + (size_t)t * CD);
    mp[0] = make_float4(o[0], o[1], o[2], o[3]);
    mp[1] = make_float4(o[4], o[5], o[6], o[7]);
}

// ---------------- agg1 wide: 16 lanes per node, coalesced segmented sum ----------------
__global__ __launch_bounds__(256) void k_agg1w(
    const float* __restrict__ msgs, const unsigned* __restrict__ nptr,
    const float* __restrict__ hroot, const float* __restrict__ bias1,
    float* __restrict__ x1pre) {
    int tid = blockIdx.x * 256 + threadIdx.x;
    int i = tid >> 4;        // node
    int l = tid & 15;        // lane in 16-group
    if (i >= NN) return;
    unsigned p0 = nptr[i], p1 = nptr[i + 1];
    int q = l & 1, roff = l >> 1;
    float4 acc = make_float4(0.f, 0.f, 0.f, 0.f);
    for (unsigned r = p0 + roff; r < p1; r += 8) {
        float4 m = *reinterpret_cast<const float4*>(msgs + (size_t)r * CD + q * 4);
        acc.x += m.x; acc.y += m.y; acc.z += m.z; acc.w += m.w;
    }
#pragma unroll
    for (int off = 2; off <= 8; off <<= 1) {
        acc.x += __shfl_down(acc.x, off);
        acc.y += __shfl_down(acc.y, off);
        acc.z += __shfl_down(acc.z, off);
        acc.w += __shfl_down(acc.w, off);
    }
    if (l < 2) {
        float4 hr = *reinterpret_cast<const float4*>(hroot + (size_t)i * CD + q * 4);
        float4 v;
        v.x = fmaxf(acc.x + hr.x + bias1[q * 4 + 0], 0.f);
        v.y = fmaxf(acc.y + hr.y + bias1[q * 4 + 1], 0.f);
        v.z = fmaxf(acc.z + hr.z + bias1[q * 4 + 2], 0.f);
        v.w = fmaxf(acc.w + hr.w + bias1[q * 4 + 3], 0.f);
        *reinterpret_cast<float4*>(x1pre + (size_t)i * CD + q * 4) = v;
    }
}

// ---------------- BN stats from x1pre (1 thread/node) ----------------
__global__ __launch_bounds__(256) void k_bnstat(
    const float* __restrict__ x1pre, float* __restrict__ bnstat) {
    int i = blockIdx.x * 256 + threadIdx.x;
    float v[CD], sq[CD];
    if (i < NN) {
        const float4* xr = reinterpret_cast<const float4*>(x1pre + (size_t)i * CD);
        float4 v0 = xr[0], v1 = xr[1];
        v[0] = v0.x; v[1] = v0.y; v[2] = v0.z; v[3] = v0.w;
        v[4] = v1.x; v[5] = v1.y; v[6] = v1.z; v[7] = v1.w;
    } else {
#pragma unroll
        for (int j = 0; j < CD; ++j) v[j] = 0.f;
    }
#pragma unroll
    for (int j = 0; j < CD; ++j) sq[j] = v[j] * v[j];
#pragma unroll
    for (int off = 32; off > 0; off >>= 1) {
#pragma unroll
        for (int j = 0; j < CD; ++j) {
            v[j] += __shfl_down(v[j], off);
            sq[j] += __shfl_down(sq[j], off);
        }
    }
    if ((threadIdx.x & 63) == 0) {
#pragma unroll
        for (int j = 0; j < CD; ++j) {
            atomicAdd(&bnstat[j], v[j]);
            atomicAdd(&bnstat[CD + j], sq[j]);
        }
    }
}

// ---------------- BN finalize ----------------
__global__ void k_bnfin(const float* __restrict__ bnstat, const float* __restrict__ gamma,
                        const float* __restrict__ beta, float* __restrict__ sc) {
    int j = threadIdx.x;
    if (j < CD) {
        float mu = bnstat[j] / (float)NN;
        float var = bnstat[CD + j] / (float)NN - mu * mu;
        float inv = rsqrtf(var + 1e-5f);
        float s = gamma[j] * inv;
        sc[j] = s;
        sc[CD + j] = beta[j] - mu * s;
    }
}

// ---------------- prep2 ----------------
__global__ __launch_bounds__(256) void k_prep2(
    const float* __restrict__ x1pre, const float* __restrict__ sc,
    const float* __restrict__ nn2w1, float* __restrict__ x1W) {
    int i = blockIdx.x * 256 + threadIdx.x;
    if (i >= NN) return;
    const float4* xr = reinterpret_cast<const float4*>(x1pre + (size_t)i * CD);
    float4 v0 = xr[0], v1 = xr[1];
    float xn[CD];
    xn[0] = v0.x * sc[0] + sc[8];  xn[1] = v0.y * sc[1] + sc[9];
    xn[2] = v0.z * sc[2] + sc[10]; xn[3] = v0.w * sc[3] + sc[11];
    xn[4] = v1.x * sc[4] + sc[12]; xn[5] = v1.y * sc[5] + sc[13];
    xn[6] = v1.z * sc[6] + sc[14]; xn[7] = v1.w * sc[7] + sc[15];
    float xw[24];
#pragma unroll
    for (int j = 0; j < 24; ++j) xw[j] = 0.f;
#pragma unroll
    for (int k = 0; k < CD; ++k)
#pragma unroll
        for (int j = 0; j < 24; ++j) xw[j] += xn[k] * nn2w1[k * 24 + j];
    float4* xo = reinterpret_cast<float4*>(x1W + (size_t)i * 24);
#pragma unroll
    for (int q = 0; q < 6; ++q)
        xo[q] = make_float4(xw[4 * q], xw[4 * q + 1], xw[4 * q + 2], xw[4 * q + 3]);
}

// ---------------- conv2 messages (bigws): split A(8)/B(2) layout for wide agg ----------------
__global__ __launch_bounds__(256, 4) void k_conv2mr(
    const float* __restrict__ eaS, const int* __restrict__ ps2,
    const float* __restrict__ x1W,
    const float* __restrict__ w1, const float* __restrict__ b1,
    const float* __restrict__ w2, const float* __restrict__ b2,
    const float* __restrict__ w3, const float* __restrict__ b3,
    float* __restrict__ msgsA, float* __restrict__ msgsB) {
    constexpr int M = CD + D;  // 24
    int t = blockIdx.x * 256 + threadIdx.x;
    if (t >= NE) return;
    int src = ps2[t];
    float ea[D];
    const float4* eg = reinterpret_cast<const float4*>(eaS + (size_t)t * 16);
#pragma unroll
    for (int q = 0; q < 4; ++q) {
        float4 v = eg[q];
        ea[4 * q] = v.x; ea[4 * q + 1] = v.y; ea[4 * q + 2] = v.z; ea[4 * q + 3] = v.w;
    }
    float a[M];
    const float4* xg = reinterpret_cast<const float4*>(x1W + (size_t)src * 24);
#pragma unroll
    for (int q = 0; q < 6; ++q) {
        float4 v = xg[q];
        a[4 * q] = v.x; a[4 * q + 1] = v.y; a[4 * q + 2] = v.z; a[4 * q + 3] = v.w;
    }
#pragma unroll
    for (int j = 0; j < M; ++j) a[j] += b1[j];
#pragma unroll
    for (int k = 0; k < D; ++k)
#pragma unroll
        for (int j = 0; j < M; ++j) a[j] += ea[k] * w1[(CD + k) * M + j];
#pragma unroll
    for (int j = 0; j < M; ++j) a[j] = leaky(a[j]);
    float bv[M];
#pragma unroll
    for (int j = 0; j < M; ++j) bv[j] = b2[j];
#pragma unroll
    for (int k = 0; k < M; ++k)
#pragma unroll
        for (int j = 0; j < M; ++j) bv[j] += a[k] * w2[k * M + j];
#pragma unroll
    for (int j = 0; j < M; ++j) bv[j] = leaky(bv[j]);
    float o[C];
#pragma unroll
    for (int j = 0; j < C; ++j) o[j] = b3[j];
#pragma unroll
    for (int k = 0; k < M; ++k)
#pragma unroll
        for (int j = 0; j < C; ++j) o[j] += bv[k] * w3[k * C + j];
    float4* ma = reinterpret_cast<float4*>(msgsA + (size_t)t * CD);
    ma[0] = make_float4(o[0], o[1], o[2], o[3]);
    ma[1] = make_float4(o[4], o[5], o[6], o[7]);
    *reinterpret_cast<float2*>(msgsB + (size_t)t * 2) = make_float2(o[8], o[9]);
}

// ---------------- conv2 messages (mid fallback, stride-10 msgs) ----------------
__global__ __launch_bounds__(256) void k_conv2m(
    const float* __restrict__ earaw, const int* __restrict__ pe2, const int* __restrict__ ps2,
    const float* __restrict__ x1W,
    const float* __restrict__ ew1, const float* __restrict__ eb1,
    const float* __restrict__ ew2, const float* __restrict__ eb2,
    const float* __restrict__ w1, const float* __restrict__ b1,
    const float* __restrict__ w2, const float* __restrict__ b2,
    const float* __restrict__ w3, const float* __restrict__ b3,
    float* __restrict__ msgs) {
    constexpr int M = CD + D;  // 24
    int t = blockIdx.x * 256 + threadIdx.x;
    if (t >= NE) return;
    int e = pe2[t], src = ps2[t];
    float ea[D];
    edge_encode(earaw, e, ew1, eb1, ew2, eb2, ea);
    float a[M];
    const float4* xg = reinterpret_cast<const float4*>(x1W + (size_t)src * 24);
#pragma unroll
    for (int q = 0; q < 6; ++q) {
        float4 v = xg[q];
        a[4 * q] = v.x; a[4 * q + 1] = v.y; a[4 * q + 2] = v.z; a[4 * q + 3] = v.w;
    }
#pragma unroll
    for (int j = 0; j < M; ++j) a[j] += b1[j];
#pragma unroll
    for (int k = 0; k < D; ++k)
#pragma unroll
        for (int j = 0; j < M; ++j) a[j] += ea[k] * w1[(CD + k) * M + j];
#pragma unroll
    for (int j = 0; j < M; ++j) a[j] = leaky(a[j]);
    float bv[M];
#pragma unroll
    for (int j = 0; j < M; ++j) bv[j] = b2[j];
#pragma unroll
    for (int k = 0; k < M; ++k)
#pragma unroll
        for (int j = 0; j < M; ++j) bv[j] += a[k] * w2[k * M + j];
#pragma unroll
    for (int j = 0; j < M; ++j) bv[j] = leaky(bv[j]);
    float o[C];
#pragma unroll
    for (int j = 0; j < C; ++j) o[j] = b3[j];
#pragma unroll
    for (int k = 0; k < M; ++k)
#pragma unroll
        for (int j = 0; j < C; ++j) o[j] += bv[k] * w3[k * C + j];
    float2* mp = reinterpret_cast<float2*>(msgs + (size_t)t * C);
#pragma unroll
    for (int q = 0; q < 5; ++q) mp[q] = make_float2(o[2 * q], o[2 * q + 1]);
}

// ---------------- agg2 wide: 16 lanes per node over split A/B msgs ----------------
__global__ __launch_bounds__(256) void k_agg2w(
    const float* __restrict__ msgsA, const float* __restrict__ msgsB,
    const unsigned* __restrict__ nptr, float* __restrict__ agg2) {
    int tid = blockIdx.x * 256 + threadIdx.x;
    int i = tid >> 4;
    int l = tid & 15;
    if (i >= NN) return;
    unsigned p0 = nptr[i], p1 = nptr[i + 1];
    int q = l & 1, roff = l >> 1;
    float4 acc = make_float4(0.f, 0.f, 0.f, 0.f);
    float2 accB = make_float2(0.f, 0.f);
    for (unsigned r = p0 + roff; r < p1; r += 8) {
        float4 m = *reinterpret_cast<const float4*>(msgsA + (size_t)r * CD + q * 4);
        acc.x += m.x; acc.y += m.y; acc.z += m.z; acc.w += m.w;
        if (q == 0) {
            float2 b = *reinterpret_cast<const float2*>(msgsB + (size_t)r * 2);
            accB.x += b.x; accB.y += b.y;
        }
    }
#pragma unroll
    for (int off = 2; off <= 8; off <<= 1) {
        acc.x += __shfl_down(acc.x, off);
        acc.y += __shfl_down(acc.y, off);
        acc.z += __shfl_down(acc.z, off);
        acc.w += __shfl_down(acc.w, off);
        accB.x += __shfl_down(accB.x, off);
        accB.y += __shfl_down(accB.y, off);
    }
    if (l == 0) {
        *reinterpret_cast<float4*>(agg2 + (size_t)i * 12) = acc;
        *reinterpret_cast<float2*>(agg2 + (size_t)i * 12 + 8) = accB;
    } else if (l == 1) {
        *reinterpret_cast<float4*>(agg2 + (size_t)i * 12 + 4) = acc;
    }
}

// ---------------- final epilogue: 1 thread/node ----------------
__global__ __launch_bounds__(256) void k_final_epi(
    const float* __restrict__ x1pre, const float* __restrict__ sc,
    const float* __restrict__ agg2,
    const float* __restrict__ root2, const float* __restrict__ bias2,
    const float* __restrict__ fcw, const float* __restrict__ fcb,
    float* __restrict__ out) {
    int i = blockIdx.x * 256 + threadIdx.x;
    if (i >= NN) return;
    float z[CD + C];
    const float4* xr = reinterpret_cast<const float4*>(x1pre + (size_t)i * CD);
    float4 v0 = xr[0], v1 = xr[1];
    z[0] = v0.x; z[1] = v0.y; z[2] = v0.z; z[3] = v0.w;
    z[4] = v1.x; z[5] = v1.y; z[6] = v1.z; z[7] = v1.w;
#pragma unroll
    for (int j = 0; j < CD; ++j) z[j] = z[j] * sc[j] + sc[CD + j];
    float x2[C];
    {
        const float4* ag = reinterpret_cast<const float4*>(agg2 + (size_t)i * 12);
        float4 a0 = ag[0], a1 = ag[1];
        float2 a2 = *reinterpret_cast<const float2*>(agg2 + (size_t)i * 12 + 8);
        x2[0] = bias2[0] + a0.x; x2[1] = bias2[1] + a0.y;
        x2[2] = bias2[2] + a0.z; x2[3] = bias2[3] + a0.w;
        x2[4] = bias2[4] + a1.x; x2[5] = bias2[5] + a1.y;
        x2[6] = bias2[6] + a1.z; x2[7] = bias2[7] + a1.w;
        x2[8] = bias2[8] + a2.x; x2[9] = bias2[9] + a2.y;
    }
#pragma unroll
    for (int k = 0; k < CD; ++k)
#pragma unroll
        for (int j = 0; j < C; ++j) x2[j] += z[k] * root2[k * C + j];
#pragma unroll
    for (int j = 0; j < C; ++j) z[CD + j] = fmaxf(x2[j], 0.f);
    float lg[C];
#pragma unroll
    for (int j = 0; j < C; ++j) lg[j] = fcb[j];
#pragma unroll
    for (int k = 0; k < CD + C; ++k)
#pragma unroll
        for (int j = 0; j < C; ++j) lg[j] += z[k] * fcw[k * C + j];
    float mx = lg[0];
#pragma unroll
    for (int j = 1; j < C; ++j) mx = fmaxf(mx, lg[j]);
    float se = 0.f;
#pragma unroll
    for (int j = 0; j < C; ++j) se += __expf(lg[j] - mx);
    float ls = __logf(se) + mx;
    float* op = out + (size_t)i * C;
#pragma unroll
    for (int j = 0; j < C; ++j) op[j] = lg[j] - ls;
}

// ---------------- final (mid fallback): 1 thread/node segmented sum over stride-10 msgs ----------------
__global__ __launch_bounds__(256) void k_finalm2(
    const float* __restrict__ x1pre, const float* __restrict__ sc,
    const float* __restrict__ msgs, const unsigned* __restrict__ nptr,
    const float* __restrict__ root2, const float* __restrict__ bias2,
    const float* __restrict__ fcw, const float* __restrict__ fcb,
    float* __restrict__ out) {
    int i = blockIdx.x * 256 + threadIdx.x;
    if (i >= NN) return;
    float z[CD + C];
    const float4* xr = reinterpret_cast<const float4*>(x1pre + (size_t)i * CD);
    float4 v0 = xr[0], v1 = xr[1];
    z[0] = v0.x; z[1] = v0.y; z[2] = v0.z; z[3] = v0.w;
    z[4] = v1.x; z[5] = v1.y; z[6] = v1.z; z[7] = v1.w;
#pragma unroll
    for (int j = 0; j < CD; ++j) z[j] = z[j] * sc[j] + sc[CD + j];
    float x2[C];
#pragma unroll
    for (int j = 0; j < C; ++j) x2[j] = bias2[j];
    unsigned p0 = nptr[i], p1 = nptr[i + 1];
#pragma unroll 4
    for (unsigned p = p0; p < p1; ++p) {
        const float2* mp = reinterpret_cast<const float2*>(msgs + (size_t)p * C);
#pragma unroll
        for (int q = 0; q < 5; ++q) {
            float2 m = mp[q];
            x2[2 * q] += m.x; x2[2 * q + 1] += m.y;
        }
    }
#pragma unroll
    for (int k = 0; k < CD; ++k)
#pragma unroll
        for (int j = 0; j < C; ++j) x2[j] += z[k] * root2[k * C + j];
#pragma unroll
    for (int j = 0; j < C; ++j) z[CD + j] = fmaxf(x2[j], 0.f);
    float lg[C];
#pragma unroll
    for (int j = 0; j < C; ++j) lg[j] = fcb[j];
#pragma unroll
    for (int k = 0; k < CD + C; ++k)
#pragma unroll
        for (int j = 0; j < C; ++j) lg[j] += z[k] * fcw[k * C + j];
    float mx = lg[0];
#pragma unroll
    for (int j = 1; j < C; ++j) mx = fmaxf(mx, lg[j]);
    float se = 0.f;
#pragma unroll
    for (int j = 0; j < C; ++j) se += __expf(lg[j] - mx);
    float ls = __logf(se) + mx;
    float* op = out + (size_t)i * C;
#pragma unroll
    for (int j = 0; j < C; ++j) op[j] = lg[j] - ls;
}

// ================= atomic fallback kernels =================
__global__ __launch_bounds__(256) void k_conv1(
    const float* __restrict__ earaw, const int* __restrict__ ei, const float* __restrict__ h,
    const float* __restrict__ ew1, const float* __restrict__ eb1,
    const float* __restrict__ ew2, const float* __restrict__ eb2,
    const float* __restrict__ w1, const float* __restrict__ b1,
    const float* __restrict__ w2, const float* __restrict__ b2,
    const float* __restrict__ w3, const float* __restrict__ b3,
    float* __restrict__ agg) {
    int e = blockIdx.x * 256 + threadIdx.x;
    if (e >= NE) return;
    int src = ei[e], dst = ei[NE + e];
    float a[32];
    edge_encode(earaw, e, ew1, eb1, ew2, eb2, a + D);
    const float4* hr = reinterpret_cast<const float4*>(h + (size_t)src * D);
#pragma unroll
    for (int q = 0; q < 4; ++q) {
        float4 v = hr[q];
        a[4 * q] = v.x; a[4 * q + 1] = v.y; a[4 * q + 2] = v.z; a[4 * q + 3] = v.w;
    }
    float o[CD];
    mlp1(a, w1, b1, w2, b2, w3, b3, o);
    float* ap = agg + (size_t)dst * CD;
#pragma unroll
    for (int j = 0; j < CD; ++j) atomicAdd(ap + j, o[j]);
}

__global__ __launch_bounds__(256) void k_conv2(
    const float* __restrict__ earaw, const int* __restrict__ ei,
    const float* __restrict__ x1pre, const float* __restrict__ sc,
    const float* __restrict__ ew1, const float* __restrict__ eb1,
    const float* __restrict__ ew2, const float* __restrict__ eb2,
    const float* __restrict__ w1, const float* __restrict__ b1,
    const float* __restrict__ w2, const float* __restrict__ b2,
    const float* __restrict__ w3, const float* __restrict__ b3,
    float* __restrict__ agg2) {
    int e = blockIdx.x * 256 + threadIdx.x;
    if (e >= NE) return;
    int src = ei[e], dst = ei[NE + e];
    float a[CD + D];
    edge_encode(earaw, e, ew1, eb1, ew2, eb2, a + CD);
    const float4* xr = reinterpret_cast<const float4*>(x1pre + (size_t)src * CD);
    float4 v0 = xr[0], v1 = xr[1];
    a[0] = v0.x * sc[0] + sc[8];  a[1] = v0.y * sc[1] + sc[9];
    a[2] = v0.z * sc[2] + sc[10]; a[3] = v0.w * sc[3] + sc[11];
    a[4] = v1.x * sc[4] + sc[12]; a[5] = v1.y * sc[5] + sc[13];
    a[6] = v1.z * sc[6] + sc[14]; a[7] = v1.w * sc[7] + sc[15];
    float o[C];
    mlp2(a, w1, b1, w2, b2, w3, b3, o);
    float* ap = agg2 + (size_t)dst * C;
#pragma unroll
    for (int j = 0; j < C; ++j) atomicAdd(ap + j, o[j]);
}

__global__ __launch_bounds__(256) void k_node1(
    const float* __restrict__ agg, const float* __restrict__ h,
    const float* __restrict__ root1, const float* __restrict__ bias1,
    float* __restrict__ x1pre, float* __restrict__ bnstat) {
    int i = blockIdx.x * 256 + threadIdx.x;
    float v[CD], sq[CD];
    if (i < NN) {
        float hv[D];
        const float4* hr = reinterpret_cast<const float4*>(h + (size_t)i * D);
#pragma unroll
        for (int q = 0; q < 4; ++q) {
            float4 w = hr[q];
            hv[4 * q] = w.x; hv[4 * q + 1] = w.y; hv[4 * q + 2] = w.z; hv[4 * q + 3] = w.w;
        }
#pragma unroll
        for (int j = 0; j < CD; ++j) v[j] = bias1[j] + agg[(size_t)i * CD + j];
#pragma unroll
        for (int k = 0; k < D; ++k)
#pragma unroll
            for (int j = 0; j < CD; ++j) v[j] += hv[k] * root1[k * CD + j];
#pragma unroll
        for (int j = 0; j < CD; ++j) v[j] = fmaxf(v[j], 0.f);
#pragma unroll
        for (int j = 0; j < CD; ++j) x1pre[(size_t)i * CD + j] = v[j];
    } else {
#pragma unroll
        for (int j = 0; j < CD; ++j) v[j] = 0.f;
    }
#pragma unroll
    for (int j = 0; j < CD; ++j) sq[j] = v[j] * v[j];
#pragma unroll
    for (int off = 32; off > 0; off >>= 1) {
#pragma unroll
        for (int j = 0; j < CD; ++j) {
            v[j] += __shfl_down(v[j], off);
            sq[j] += __shfl_down(sq[j], off);
        }
    }
    if ((threadIdx.x & 63) == 0) {
#pragma unroll
        for (int j = 0; j < CD; ++j) {
            atomicAdd(&bnstat[j], v[j]);
            atomicAdd(&bnstat[CD + j], sq[j]);
        }
    }
}

__global__ __launch_bounds__(256) void k_final(
    const float* __restrict__ x1pre, const float* __restrict__ sc,
    const float* __restrict__ agg2, const float* __restrict__ root2,
    const float* __restrict__ bias2, const float* __restrict__ fcw,
    const float* __restrict__ fcb, float* __restrict__ out) {
    int i = blockIdx.x * 256 + threadIdx.x;
    if (i >= NN) return;
    float z[CD + C];
    const float4* xr = reinterpret_cast<const float4*>(x1pre + (size_t)i * CD);
    float4 v0 = xr[0], v1 = xr[1];
    z[0] = v0.x; z[1] = v0.y; z[2] = v0.z; z[3] = v0.w;
    z[4] = v1.x; z[5] = v1.y; z[6] = v1.z; z[7] = v1.w;
#pragma unroll
    for (int j = 0; j < CD; ++j) z[j] = z[j] * sc[j] + sc[CD + j];
    float x2[C];
#pragma unroll
    for (int j = 0; j < C; ++j) x2[j] = bias2[j] + agg2[(size_t)i * C + j];
#pragma unroll
    for (int k = 0; k < CD; ++k)
#pragma unroll
        for (int j = 0; j < C; ++j) x2[j] += z[k] * root2[k * C + j];
#pragma unroll
    for (int j = 0; j < C; ++j) z[CD + j] = fmaxf(x2[j], 0.f);
    float lg[C];
#pragma unroll
    for (int j = 0; j < C; ++j) lg[j] = fcb[j];
#pragma unroll
    for (int k = 0; k < CD + C; ++k)
#pragma unroll
        for (int j = 0; j < C; ++j) lg[j] += z[k] * fcw[k * C + j];
    float mx = lg[0];
#pragma unroll
    for (int j = 1; j < C; ++j) mx = fmaxf(mx, lg[j]);
    float se = 0.f;
#pragma unroll
    for (int j = 0; j < C; ++j) se += __expf(lg[j] - mx);
    float ls = __logf(se) + mx;
    float* op = out + (size_t)i * C;
#pragma unroll
    for (int j = 0; j < C; ++j) op[j] = lg[j] - ls;
}

extern "C" void kernel_launch(void* const* d_in, const int* in_sizes, int n_in,
                              void* d_out, int out_size, void* d_ws, size_t ws_size,
                              hipStream_t stream) {
    const float* x      = (const float*)d_in[0];
    const float* earaw  = (const float*)d_in[1];
    const float* twin   = (const float*)d_in[2];
    const int*   ei     = (const int*)d_in[3];
    const float* ne_w1  = (const float*)d_in[4];
    const float* ne_b1  = (const float*)d_in[5];
    const float* ne_w2  = (const float*)d_in[6];
    const float* ne_b2  = (const float*)d_in[7];
    const float* ee_w1  = (const float*)d_in[8];
    const float* ee_b1  = (const float*)d_in[9];
    const float* ee_w2  = (const float*)d_in[10];
    const float* ee_b2  = (const float*)d_in[11];
    const float* tw_w   = (const float*)d_in[12];
    const float* tw_b   = (const float*)d_in[13];
    const float* nn1_w1 = (const float*)d_in[14];
    const float* nn1_b1 = (const float*)d_in[15];
    const float* nn1_w2 = (const float*)d_in[16];
    const float* nn1_b2 = (const float*)d_in[17];
    const float* nn1_w3 = (const float*)d_in[18];
    const float* nn1_b3 = (const float*)d_in[19];
    const float* root1  = (const float*)d_in[20];
    const float* bias1  = (const float*)d_in[21];
    const float* bn_g   = (const float*)d_in[22];
    const float* bn_b   = (const float*)d_in[23];
    const float* nn2_w1 = (const float*)d_in[24];
    const float* nn2_b1 = (const float*)d_in[25];
    const float* nn2_w2 = (const float*)d_in[26];
    const float* nn2_b2 = (const float*)d_in[27];
    const float* nn2_w3 = (const float*)d_in[28];
    const float* nn2_b3 = (const float*)d_in[29];
    const float* root2  = (const float*)d_in[30];
    const float* bias2  = (const float*)d_in[31];
    const float* fc_w   = (const float*)d_in[32];
    const float* fc_b   = (const float*)d_in[33];
    float* out = (float*)d_out;
    float* ws = (float*)d_ws;

    // ---------- sorted-path layout (floats) ----------
    const size_t f_hW1    = 0;            // NN*32
    const size_t f_hroot  = 3200000;      // NN*8
    const size_t f_x1pre  = 4000000;      // NN*8
    const size_t f_x1W    = 4800000;      // NN*24
    const size_t f_bn     = 7200000;      // 32
    const size_t f_total  = 7200032;      // 256
    const size_t f_bstart = 7200288;      // 320
    const size_t f_histp  = 7200608;      // 65536
    const size_t f_offp   = 7266144;      // 65536
    const size_t f_nptr   = 7331680;      // 100352
    const size_t f_pe     = 7432032;      // NE (dead after sort2; agg2 overlays: NN*12)
    const size_t f_ps     = 9032032;      // NE
    const size_t f_pd     = 10632032;     // NE
    const size_t f_pe2    = 12232032;     // NE
    const size_t f_ps2    = 13832032;     // NE
    const size_t f_msgs   = 15432032;     // NE*10 (conv1: NE*8; conv2: A=NE*8 + B=NE*2)
    const size_t f_endB   = 31432032;     // mid path end
    const size_t f_eaS    = 31432032;     // NE*16
    const size_t f_endA   = 57032032;     // +eaS

    if (ws_size >= f_endB * sizeof(float)) {
        float* hW1    = ws + f_hW1;
        float* hroot  = ws + f_hroot;
        float* x1pre  = ws + f_x1pre;
        float* x1W    = ws + f_x1W;
        float* bnstat = ws + f_bn;
        float* sc     = ws + f_bn + 16;
        unsigned* total  = (unsigned*)(ws + f_total);
        unsigned* bstart = (unsigned*)(ws + f_bstart);
        unsigned* histp  = (unsigned*)(ws + f_histp);
        unsigned* offp   = (unsigned*)(ws + f_offp);
        unsigned* nptr   = (unsigned*)(ws + f_nptr);
        int* pe  = (int*)(ws + f_pe);
        int* ps  = (int*)(ws + f_ps);
        int* pd  = (int*)(ws + f_pd);
        int* pe2 = (int*)(ws + f_pe2);
        int* ps2 = (int*)(ws + f_ps2);
        float* msgs  = ws + f_msgs;             // conv1 msgs, stride 8
        float* msgsB = ws + f_msgs + (size_t)NE * 8;  // conv2 cols 8-9, stride 2
        float* agg2  = ws + f_pe;               // NN*12, overlays dead pe
        float* eaS   = ws + f_eaS;
        bool bigws = ws_size >= f_endA * sizeof(float);

        k_node_enc2<<<(NN + 255) / 256, 256, 0, stream>>>(
            x, twin, ne_w1, ne_b1, ne_w2, ne_b2, tw_w, tw_b, nn1_w1, root1, hW1, hroot);
        k_hist<<<NBLK, 256, 0, stream>>>(ei, histp);
        k_scanA<<<NB, 256, 0, stream>>>(histp, offp, total);
        k_scanB<<<1, 256, 0, stream>>>(total, bstart, bnstat);
        k_scatter<<<NBLK, 256, 0, stream>>>(ei, offp, bstart, pe, ps, pd);
        k_sort2<<<NB, 256, 0, stream>>>(pe, ps, pd, bstart, pe2, ps2, nptr);
        if (bigws) {
            k_conv1mw<<<(NE + 255) / 256, 256, 0, stream>>>(
                earaw, pe2, ps2, hW1, ee_w1, ee_b1, ee_w2, ee_b2,
                nn1_w1, nn1_b1, nn1_w2, nn1_b2, nn1_w3, nn1_b3, msgs, eaS);
        } else {
            k_conv1m<<<(NE + 255) / 256, 256, 0, stream>>>(
                earaw, pe2, ps2, hW1, ee_w1, ee_b1, ee_w2, ee_b2,
                nn1_w1, nn1_b1, nn1_w2, nn1_b2, nn1_w3, nn1_b3, msgs);
        }
        k_agg1w<<<AGG_BLOCKS, 256, 0, stream>>>(msgs, nptr, hroot, bias1, x1pre);
        k_bnstat<<<(NN + 255) / 256, 256, 0, stream>>>(x1pre, bnstat);
        k_bnfin<<<1, 64, 0, stream>>>(bnstat, bn_g, bn_b, sc);
        k_prep2<<<(NN + 255) / 256, 256, 0, stream>>>(x1pre, sc, nn2_w1, x1W);
        if (bigws) {
            k_conv2mr<<<(NE + 255) / 256, 256, 0, stream>>>(
                eaS, ps2, x1W,
                nn2_w1, nn2_b1, nn2_w2, nn2_b2, nn2_w3, nn2_b3, msgs, msgsB);
            k_agg2w<<<AGG_BLOCKS, 256, 0, stream>>>(msgs, msgsB, nptr, agg2);
            k_final_epi<<<(NN + 255) / 256, 256, 0, stream>>>(
                x1pre, sc, agg2, root2, bias2, fc_w, fc_b, out);
        } else {
            k_conv2m<<<(NE + 255) / 256, 256, 0, stream>>>(
                earaw, pe2, ps2, x1W, ee_w1, ee_b1, ee_w2, ee_b2,
                nn2_w1, nn2_b1, nn2_w2, nn2_b2, nn2_w3, nn2_b3, msgs);
            k_finalm2<<<(NN + 255) / 256, 256, 0, stream>>>(
                x1pre, sc, msgs, nptr, root2, bias2, fc_w, fc_b, out);
        }
    } else {
        // fallback: atomic path
        float* h     = ws;
        float* x1pre = ws + (size_t)NN * 16;
        float* agg   = ws + (size_t)NN * 24;
        float* agg2  = ws + (size_t)NN * 32;
        float* bnst  = ws + (size_t)NN * 42;
        float* scf   = bnst + 16;
        int zn = NN * 18 + 16;
        k_zero<<<(zn + 255) / 256, 256, 0, stream>>>(agg, zn);
        k_node_enc<<<(NN + 255) / 256, 256, 0, stream>>>(
            x, twin, ne_w1, ne_b1, ne_w2, ne_b2, tw_w, tw_b, h);
        k_conv1<<<(NE + 255) / 256, 256, 0, stream>>>(
            earaw, ei, h, ee_w1, ee_b1, ee_w2, ee_b2,
            nn1_w1, nn1_b1, nn1_w2, nn1_b2, nn1_w3, nn1_b3, agg);
        k_node1<<<(NN + 255) / 256, 256, 0, stream>>>(
            agg, h, root1, bias1, x1pre, bnst);
        k_bnfin<<<1, 64, 0, stream>>>(bnst, bn_g, bn_b, scf);
        k_conv2<<<(NE + 255) / 256, 256, 0, stream>>>(
            earaw, ei, x1pre, scf, ee_w1, ee_b1, ee_w2, ee_b2,
            nn2_w1, nn2_b1, nn2_w2, nn2_b2, nn2_w3, nn2_b3, agg2);
        k_final<<<(NN + 255) / 256, 256, 0, stream>>>(
            x1pre, scf, agg2, root2, bias2, fc_w, fc_b, out);
    }
}

// Round 9
// 782.436 us; speedup vs baseline: 1.3966x; 1.3966x over previous
//
#include <hip/hip_runtime.h>
#include <math.h>

#define NN 100000
#define NE 1600000
constexpr int IN_DIM = 128;
constexpr int ED_DIM = 16;
constexpr int D = 16;
constexpr int CD = 8;
constexpr int C = 10;

constexpr int NB   = 256;                 // dst buckets
constexpr int NR   = 391;                 // nodes per bucket
constexpr int NBT  = NB * NR;             // 100096
constexpr int NBLK = 256;                 // blocks for hist/scatter
constexpr int EPB  = (NE + NBLK - 1) / NBLK;  // 6250
constexpr int AGG_BLOCKS = (NN * 16 + 255) / 256;  // 6250: 16 lanes per node
constexpr int BN_BLOCKS = (NN + 255) / 256;        // 391

__device__ __forceinline__ float leaky(float v) { return v >= 0.f ? v : 0.01f * v; }

// ---------- edge encoder helper ----------
__device__ __forceinline__ void edge_encode(
    const float* __restrict__ earaw, int e,
    const float* __restrict__ ew1, const float* __restrict__ eb1,
    const float* __restrict__ ew2, const float* __restrict__ eb2,
    float* __restrict__ ea /*16*/) {
    float r[ED_DIM];
    const float4* er = reinterpret_cast<const float4*>(earaw + (size_t)e * ED_DIM);
#pragma unroll
    for (int q = 0; q < 4; ++q) {
        float4 v = er[q];
        r[4 * q] = v.x; r[4 * q + 1] = v.y; r[4 * q + 2] = v.z; r[4 * q + 3] = v.w;
    }
    float t[D];
#pragma unroll
    for (int j = 0; j < D; ++j) t[j] = eb1[j];
#pragma unroll
    for (int k = 0; k < ED_DIM; ++k)
#pragma unroll
        for (int j = 0; j < D; ++j) t[j] += r[k] * ew1[k * D + j];
#pragma unroll
    for (int j = 0; j < D; ++j) t[j] = leaky(t[j]);
#pragma unroll
    for (int j = 0; j < D; ++j) ea[j] = eb2[j];
#pragma unroll
    for (int k = 0; k < D; ++k)
#pragma unroll
        for (int j = 0; j < D; ++j) ea[j] += t[k] * ew2[k * D + j];
}

__device__ __forceinline__ void mlp1(
    float* __restrict__ a /*32 in, clobbered*/,
    const float* __restrict__ w1, const float* __restrict__ b1,
    const float* __restrict__ w2, const float* __restrict__ b2,
    const float* __restrict__ w3, const float* __restrict__ b3,
    float* __restrict__ o /*8*/) {
    float bv[32];
#pragma unroll
    for (int j = 0; j < 32; ++j) bv[j] = b1[j];
#pragma unroll
    for (int k = 0; k < 32; ++k)
#pragma unroll
        for (int j = 0; j < 32; ++j) bv[j] += a[k] * w1[k * 32 + j];
#pragma unroll
    for (int j = 0; j < 32; ++j) bv[j] = leaky(bv[j]);
#pragma unroll
    for (int j = 0; j < 32; ++j) a[j] = b2[j];
#pragma unroll
    for (int k = 0; k < 32; ++k)
#pragma unroll
        for (int j = 0; j < 32; ++j) a[j] += bv[k] * w2[k * 32 + j];
#pragma unroll
    for (int j = 0; j < 32; ++j) a[j] = leaky(a[j]);
#pragma unroll
    for (int j = 0; j < CD; ++j) o[j] = b3[j];
#pragma unroll
    for (int k = 0; k < 32; ++k)
#pragma unroll
        for (int j = 0; j < CD; ++j) o[j] += a[k] * w3[k * CD + j];
}

__device__ __forceinline__ void mlp2(
    float* __restrict__ a /*24 in, clobbered*/,
    const float* __restrict__ w1, const float* __restrict__ b1,
    const float* __restrict__ w2, const float* __restrict__ b2,
    const float* __restrict__ w3, const float* __restrict__ b3,
    float* __restrict__ o /*10*/) {
    constexpr int M = CD + D;  // 24
    float bv[M];
#pragma unroll
    for (int j = 0; j < M; ++j) bv[j] = b1[j];
#pragma unroll
    for (int k = 0; k < M; ++k)
#pragma unroll
        for (int j = 0; j < M; ++j) bv[j] += a[k] * w1[k * M + j];
#pragma unroll
    for (int j = 0; j < M; ++j) bv[j] = leaky(bv[j]);
#pragma unroll
    for (int j = 0; j < M; ++j) a[j] = b2[j];
#pragma unroll
    for (int k = 0; k < M; ++k)
#pragma unroll
        for (int j = 0; j < M; ++j) a[j] += bv[k] * w2[k * M + j];
#pragma unroll
    for (int j = 0; j < M; ++j) a[j] = leaky(a[j]);
#pragma unroll
    for (int j = 0; j < C; ++j) o[j] = b3[j];
#pragma unroll
    for (int k = 0; k < M; ++k)
#pragma unroll
        for (int j = 0; j < C; ++j) o[j] += a[k] * w3[k * C + j];
}

// ---------------- zero region (fallback only) ----------------
__global__ __launch_bounds__(256) void k_zero(float* __restrict__ p, int n) {
    int i = blockIdx.x * 256 + threadIdx.x;
    if (i < n) p[i] = 0.f;
}

// ---------------- node encoder (sorted paths): writes hW1[32] and hroot[8] per node ----------------
__global__ __launch_bounds__(256) void k_node_enc2(
    const float* __restrict__ x, const float* __restrict__ twin,
    const float* __restrict__ w1, const float* __restrict__ b1,
    const float* __restrict__ w2, const float* __restrict__ b2,
    const float* __restrict__ tww, const float* __restrict__ twb,
    const float* __restrict__ nn1w1, const float* __restrict__ root1,
    float* __restrict__ hW1, float* __restrict__ hroot) {
    int i = blockIdx.x * 256 + threadIdx.x;
    if (i >= NN) return;
    float acc[D];
#pragma unroll
    for (int j = 0; j < D; ++j) acc[j] = b1[j];
    const float4* xr = reinterpret_cast<const float4*>(x + (size_t)i * IN_DIM);
#pragma unroll 8
    for (int k4 = 0; k4 < IN_DIM / 4; ++k4) {
        float4 xv = xr[k4];
        const float* wr = w1 + (k4 * 4) * D;
#pragma unroll
        for (int j = 0; j < D; ++j) acc[j] += xv.x * wr[j];
#pragma unroll
        for (int j = 0; j < D; ++j) acc[j] += xv.y * wr[D + j];
#pragma unroll
        for (int j = 0; j < D; ++j) acc[j] += xv.z * wr[2 * D + j];
#pragma unroll
        for (int j = 0; j < D; ++j) acc[j] += xv.w * wr[3 * D + j];
    }
    float t[D];
#pragma unroll
    for (int j = 0; j < D; ++j) t[j] = leaky(acc[j]);
    float h2[D];
#pragma unroll
    for (int j = 0; j < D; ++j) h2[j] = b2[j];
#pragma unroll
    for (int k = 0; k < D; ++k)
#pragma unroll
        for (int j = 0; j < D; ++j) h2[j] += t[k] * w2[k * D + j];
    float twv = twin[i];
#pragma unroll
    for (int j = 0; j < D; ++j) h2[j] *= (twv * tww[j] + twb[j]);
    float hw[32];
#pragma unroll
    for (int j = 0; j < 32; ++j) hw[j] = 0.f;
#pragma unroll
    for (int k = 0; k < D; ++k)
#pragma unroll
        for (int j = 0; j < 32; ++j) hw[j] += h2[k] * nn1w1[k * 32 + j];
    float4* hwo = reinterpret_cast<float4*>(hW1 + (size_t)i * 32);
#pragma unroll
    for (int q = 0; q < 8; ++q)
        hwo[q] = make_float4(hw[4 * q], hw[4 * q + 1], hw[4 * q + 2], hw[4 * q + 3]);
    float hr[CD];
#pragma unroll
    for (int j = 0; j < CD; ++j) hr[j] = 0.f;
#pragma unroll
    for (int k = 0; k < D; ++k)
#pragma unroll
        for (int j = 0; j < CD; ++j) hr[j] += h2[k] * root1[k * CD + j];
    float4* hro = reinterpret_cast<float4*>(hroot + (size_t)i * CD);
    hro[0] = make_float4(hr[0], hr[1], hr[2], hr[3]);
    hro[1] = make_float4(hr[4], hr[5], hr[6], hr[7]);
}

// ---------------- node encoder (atomic fallback): writes h[16] ----------------
__global__ __launch_bounds__(256) void k_node_enc(
    const float* __restrict__ x, const float* __restrict__ twin,
    const float* __restrict__ w1, const float* __restrict__ b1,
    const float* __restrict__ w2, const float* __restrict__ b2,
    const float* __restrict__ tww, const float* __restrict__ twb,
    float* __restrict__ hout) {
    int i = blockIdx.x * 256 + threadIdx.x;
    if (i >= NN) return;
    float acc[D];
#pragma unroll
    for (int j = 0; j < D; ++j) acc[j] = b1[j];
    const float4* xr = reinterpret_cast<const float4*>(x + (size_t)i * IN_DIM);
#pragma unroll 8
    for (int k4 = 0; k4 < IN_DIM / 4; ++k4) {
        float4 xv = xr[k4];
        const float* wr = w1 + (k4 * 4) * D;
#pragma unroll
        for (int j = 0; j < D; ++j) acc[j] += xv.x * wr[j];
#pragma unroll
        for (int j = 0; j < D; ++j) acc[j] += xv.y * wr[D + j];
#pragma unroll
        for (int j = 0; j < D; ++j) acc[j] += xv.z * wr[2 * D + j];
#pragma unroll
        for (int j = 0; j < D; ++j) acc[j] += xv.w * wr[3 * D + j];
    }
    float t[D];
#pragma unroll
    for (int j = 0; j < D; ++j) t[j] = leaky(acc[j]);
    float h2[D];
#pragma unroll
    for (int j = 0; j < D; ++j) h2[j] = b2[j];
#pragma unroll
    for (int k = 0; k < D; ++k)
#pragma unroll
        for (int j = 0; j < D; ++j) h2[j] += t[k] * w2[k * D + j];
    float twv = twin[i];
#pragma unroll
    for (int j = 0; j < D; ++j) h2[j] *= (twv * tww[j] + twb[j]);
    float4* ho = reinterpret_cast<float4*>(hout + (size_t)i * D);
#pragma unroll
    for (int q = 0; q < 4; ++q)
        ho[q] = make_float4(h2[4 * q], h2[4 * q + 1], h2[4 * q + 2], h2[4 * q + 3]);
}

// ---------------- sort level 1 ----------------
__global__ __launch_bounds__(256) void k_hist(const int* __restrict__ ei,
                                              unsigned* __restrict__ histp) {
    __shared__ unsigned hist[NB];
    int tid = threadIdx.x, blk = blockIdx.x;
    hist[tid] = 0;
    __syncthreads();
    int lo = blk * EPB, hi = min(lo + EPB, NE);
    for (int t = lo + tid; t < hi; t += 256) {
        int dst = ei[NE + t];
        atomicAdd(&hist[dst / NR], 1u);
    }
    __syncthreads();
    histp[tid * NBLK + blk] = hist[tid];  // [bin][blk]
}

__global__ __launch_bounds__(256) void k_scanA(const unsigned* __restrict__ histp,
                                               unsigned* __restrict__ offp,
                                               unsigned* __restrict__ total) {
    __shared__ unsigned buf[256];
    int j = blockIdx.x, t = threadIdx.x;
    unsigned v = histp[j * NBLK + t];
    buf[t] = v;
    __syncthreads();
    for (int d = 1; d < 256; d <<= 1) {
        unsigned add = (t >= d) ? buf[t - d] : 0u;
        __syncthreads();
        buf[t] += add;
        __syncthreads();
    }
    offp[j * NBLK + t] = buf[t] - v;
    if (t == 255) total[j] = buf[255];
}

__global__ __launch_bounds__(256) void k_scanB(const unsigned* __restrict__ total,
                                               unsigned* __restrict__ bstart,
                                               float* __restrict__ bn) {
    __shared__ unsigned buf[256];
    int t = threadIdx.x;
    unsigned v = total[t];
    buf[t] = v;
    __syncthreads();
    for (int d = 1; d < 256; d <<= 1) {
        unsigned add = (t >= d) ? buf[t - d] : 0u;
        __syncthreads();
        buf[t] += add;
        __syncthreads();
    }
    bstart[t] = buf[t] - v;
    if (t == 255) bstart[256] = buf[255];
    if (t < 32) bn[t] = 0.f;
}

__global__ __launch_bounds__(256) void k_scatter(const int* __restrict__ ei,
                                                 const unsigned* __restrict__ offp,
                                                 const unsigned* __restrict__ bstart,
                                                 int* __restrict__ pe, int* __restrict__ ps,
                                                 int* __restrict__ pd) {
    __shared__ unsigned cur[NB];
    int tid = threadIdx.x, blk = blockIdx.x;
    cur[tid] = bstart[tid] + offp[tid * NBLK + blk];
    __syncthreads();
    int lo = blk * EPB, hi = min(lo + EPB, NE);
    for (int t = lo + tid; t < hi; t += 256) {
        int dst = ei[NE + t];
        int src = ei[t];
        int bin = dst / NR;
        unsigned pos = atomicAdd(&cur[bin], 1u);
        pe[pos] = t; ps[pos] = src; pd[pos] = dst;
    }
}

// ---------------- sort level 2 ----------------
__global__ __launch_bounds__(256) void k_sort2(
    const int* __restrict__ pe, const int* __restrict__ ps, const int* __restrict__ pd,
    const unsigned* __restrict__ bstart,
    int* __restrict__ pe2, int* __restrict__ ps2, unsigned* __restrict__ nptr) {
    __shared__ unsigned cnt[512];
    __shared__ unsigned cur[NR];
    int b = blockIdx.x, tid = threadIdx.x;
    int s0 = (int)bstart[b], s1 = (int)bstart[b + 1];
    int base = b * NR;
    cnt[tid] = 0; cnt[tid + 256] = 0;
    __syncthreads();
    for (int t = s0 + tid; t < s1; t += 256)
        atomicAdd(&cnt[pd[t] - base], 1u);
    __syncthreads();
    for (int d = 1; d < 512; d <<= 1) {
        unsigned v0 = (tid >= d) ? cnt[tid - d] : 0u;
        unsigned v1 = (tid + 256 >= (unsigned)d) ? cnt[tid + 256 - d] : 0u;
        __syncthreads();
        cnt[tid] += v0; cnt[tid + 256] += v1;
        __syncthreads();
    }
    for (int r = tid; r < NR; r += 256) {
        unsigned off = (r == 0) ? 0u : cnt[r - 1];
        nptr[base + r] = s0 + off;
        cur[r] = s0 + off;
    }
    if (b == NB - 1 && tid == 0) nptr[NBT] = (unsigned)s1;
    __syncthreads();
    for (int t = s0 + tid; t < s1; t += 256) {
        int r = pd[t] - base;
        unsigned pos = atomicAdd(&cur[r], 1u);
        pe2[pos] = pe[t]; ps2[pos] = ps[t];
    }
}

// ---------------- conv1 messages (writes sorted ea for conv2 reuse) ----------------
__global__ __launch_bounds__(256, 4) void k_conv1mw(
    const float* __restrict__ earaw, const int* __restrict__ pe2, const int* __restrict__ ps2,
    const float* __restrict__ hW1,
    const float* __restrict__ ew1, const float* __restrict__ eb1,
    const float* __restrict__ ew2, const float* __restrict__ eb2,
    const float* __restrict__ w1, const float* __restrict__ b1,
    const float* __restrict__ w2, const float* __restrict__ b2,
    const float* __restrict__ w3, const float* __restrict__ b3,
    float* __restrict__ msgs, float* __restrict__ eaS) {
    int t = blockIdx.x * 256 + threadIdx.x;
    if (t >= NE) return;
    int e = pe2[t], src = ps2[t];
    float ea[D];
    edge_encode(earaw, e, ew1, eb1, ew2, eb2, ea);
    float4* eo = reinterpret_cast<float4*>(eaS + (size_t)t * 16);
#pragma unroll
    for (int q = 0; q < 4; ++q)
        eo[q] = make_float4(ea[4 * q], ea[4 * q + 1], ea[4 * q + 2], ea[4 * q + 3]);
    float a[32];
    const float4* hg = reinterpret_cast<const float4*>(hW1 + (size_t)src * 32);
#pragma unroll
    for (int q = 0; q < 8; ++q) {
        float4 v = hg[q];
        a[4 * q] = v.x; a[4 * q + 1] = v.y; a[4 * q + 2] = v.z; a[4 * q + 3] = v.w;
    }
#pragma unroll
    for (int j = 0; j < 32; ++j) a[j] += b1[j];
#pragma unroll
    for (int k = 0; k < D; ++k)
#pragma unroll
        for (int j = 0; j < 32; ++j) a[j] += ea[k] * w1[(16 + k) * 32 + j];
#pragma unroll
    for (int j = 0; j < 32; ++j) a[j] = leaky(a[j]);
    float bv[32];
#pragma unroll
    for (int j = 0; j < 32; ++j) bv[j] = b2[j];
#pragma unroll
    for (int k = 0; k < 32; ++k)
#pragma unroll
        for (int j = 0; j < 32; ++j) bv[j] += a[k] * w2[k * 32 + j];
#pragma unroll
    for (int j = 0; j < 32; ++j) bv[j] = leaky(bv[j]);
    float o[CD];
#pragma unroll
    for (int j = 0; j < CD; ++j) o[j] = b3[j];
#pragma unroll
    for (int k = 0; k < 32; ++k)
#pragma unroll
        for (int j = 0; j < CD; ++j) o[j] += bv[k] * w3[k * CD + j];
    float4* mp = reinterpret_cast<float4*>(msgs + (size_t)t * CD);
    mp[0] = make_float4(o[0], o[1], o[2], o[3]);
    mp[1] = make_float4(o[4], o[5], o[6], o[7]);
}

// ---------------- conv1 messages (mid fallback, no eaS) ----------------
__global__ __launch_bounds__(256) void k_conv1m(
    const float* __restrict__ earaw, const int* __restrict__ pe2, const int* __restrict__ ps2,
    const float* __restrict__ hW1,
    const float* __restrict__ ew1, const float* __restrict__ eb1,
    const float* __restrict__ ew2, const float* __restrict__ eb2,
    const float* __restrict__ w1, const float* __restrict__ b1,
    const float* __restrict__ w2, const float* __restrict__ b2,
    const float* __restrict__ w3, const float* __restrict__ b3,
    float* __restrict__ msgs) {
    int t = blockIdx.x * 256 + threadIdx.x;
    if (t >= NE) return;
    int e = pe2[t], src = ps2[t];
    float ea[D];
    edge_encode(earaw, e, ew1, eb1, ew2, eb2, ea);
    float a[32];
    const float4* hg = reinterpret_cast<const float4*>(hW1 + (size_t)src * 32);
#pragma unroll
    for (int q = 0; q < 8; ++q) {
        float4 v = hg[q];
        a[4 * q] = v.x; a[4 * q + 1] = v.y; a[4 * q + 2] = v.z; a[4 * q + 3] = v.w;
    }
#pragma unroll
    for (int j = 0; j < 32; ++j) a[j] += b1[j];
#pragma unroll
    for (int k = 0; k < D; ++k)
#pragma unroll
        for (int j = 0; j < 32; ++j) a[j] += ea[k] * w1[(16 + k) * 32 + j];
#pragma unroll
    for (int j = 0; j < 32; ++j) a[j] = leaky(a[j]);
    float bv[32];
#pragma unroll
    for (int j = 0; j < 32; ++j) bv[j] = b2[j];
#pragma unroll
    for (int k = 0; k < 32; ++k)
#pragma unroll
        for (int j = 0; j < 32; ++j) bv[j] += a[k] * w2[k * 32 + j];
#pragma unroll
    for (int j = 0; j < 32; ++j) bv[j] = leaky(bv[j]);
    float o[CD];
#pragma unroll
    for (int j = 0; j < CD; ++j) o[j] = b3[j];
#pragma unroll
    for (int k = 0; k < 32; ++k)
#pragma unroll
        for (int j = 0; j < CD; ++j) o[j] += bv[k] * w3[k * CD + j];
    float4* mp = reinterpret_cast<float4*>(msgs + (size_t)t * CD);
    mp[0] = make_float4(o[0], o[1], o[2], o[3]);
    mp[1] = make_float4(o[4], o[5], o[6], o[7]);
}

// ---------------- agg1 wide: 16 lanes per node, coalesced segmented sum ----------------
__global__ __launch_bounds__(256) void k_agg1w(
    const float* __restrict__ msgs, const unsigned* __restrict__ nptr,
    const float* __restrict__ hroot, const float* __restrict__ bias1,
    float* __restrict__ x1pre) {
    int tid = blockIdx.x * 256 + threadIdx.x;
    int i = tid >> 4;        // node
    int l = tid & 15;        // lane in 16-group
    if (i >= NN) return;
    unsigned p0 = nptr[i], p1 = nptr[i + 1];
    int q = l & 1, roff = l >> 1;
    float4 acc = make_float4(0.f, 0.f, 0.f, 0.f);
    for (unsigned r = p0 + roff; r < p1; r += 8) {
        float4 m = *reinterpret_cast<const float4*>(msgs + (size_t)r * CD + q * 4);
        acc.x += m.x; acc.y += m.y; acc.z += m.z; acc.w += m.w;
    }
#pragma unroll
    for (int off = 2; off <= 8; off <<= 1) {
        acc.x += __shfl_down(acc.x, off);
        acc.y += __shfl_down(acc.y, off);
        acc.z += __shfl_down(acc.z, off);
        acc.w += __shfl_down(acc.w, off);
    }
    if (l < 2) {
        float4 hr = *reinterpret_cast<const float4*>(hroot + (size_t)i * CD + q * 4);
        float4 v;
        v.x = fmaxf(acc.x + hr.x + bias1[q * 4 + 0], 0.f);
        v.y = fmaxf(acc.y + hr.y + bias1[q * 4 + 1], 0.f);
        v.z = fmaxf(acc.z + hr.z + bias1[q * 4 + 2], 0.f);
        v.w = fmaxf(acc.w + hr.w + bias1[q * 4 + 3], 0.f);
        *reinterpret_cast<float4*>(x1pre + (size_t)i * CD + q * 4) = v;
    }
}

// ---------------- BN stats stage 1: per-block partials, NO global atomics ----------------
__global__ __launch_bounds__(256) void k_bnstat2(
    const float* __restrict__ x1pre, float* __restrict__ bnpart) {
    __shared__ float part[4][16];
    int i = blockIdx.x * 256 + threadIdx.x;
    float v[CD], sq[CD];
    if (i < NN) {
        const float4* xr = reinterpret_cast<const float4*>(x1pre + (size_t)i * CD);
        float4 v0 = xr[0], v1 = xr[1];
        v[0] = v0.x; v[1] = v0.y; v[2] = v0.z; v[3] = v0.w;
        v[4] = v1.x; v[5] = v1.y; v[6] = v1.z; v[7] = v1.w;
    } else {
#pragma unroll
        for (int j = 0; j < CD; ++j) v[j] = 0.f;
    }
#pragma unroll
    for (int j = 0; j < CD; ++j) sq[j] = v[j] * v[j];
#pragma unroll
    for (int off = 32; off > 0; off >>= 1) {
#pragma unroll
        for (int j = 0; j < CD; ++j) {
            v[j] += __shfl_down(v[j], off);
            sq[j] += __shfl_down(sq[j], off);
        }
    }
    int wave = threadIdx.x >> 6;
    if ((threadIdx.x & 63) == 0) {
#pragma unroll
        for (int j = 0; j < CD; ++j) {
            part[wave][j] = v[j];
            part[wave][CD + j] = sq[j];
        }
    }
    __syncthreads();
    if (threadIdx.x < 16) {
        float s = part[0][threadIdx.x] + part[1][threadIdx.x] +
                  part[2][threadIdx.x] + part[3][threadIdx.x];
        bnpart[(size_t)blockIdx.x * 16 + threadIdx.x] = s;
    }
}

// ---------------- BN stats stage 2 + finalize: one block ----------------
__global__ void k_bnfin2(const float* __restrict__ bnpart,
                         const float* __restrict__ gamma,
                         const float* __restrict__ beta, float* __restrict__ sc) {
    __shared__ float buf[16];
    int j = threadIdx.x;
    if (j < 16) {
        float s = 0.f;
        for (int p = 0; p < BN_BLOCKS; ++p) s += bnpart[(size_t)p * 16 + j];
        buf[j] = s;
    }
    __syncthreads();
    if (j < CD) {
        float mu = buf[j] / (float)NN;
        float var = buf[CD + j] / (float)NN - mu * mu;
        float inv = rsqrtf(var + 1e-5f);
        float s = gamma[j] * inv;
        sc[j] = s;
        sc[CD + j] = beta[j] - mu * s;
    }
}

// ---------------- BN finalize (atomic fallback path) ----------------
__global__ void k_bnfin(const float* __restrict__ bnstat, const float* __restrict__ gamma,
                        const float* __restrict__ beta, float* __restrict__ sc) {
    int j = threadIdx.x;
    if (j < CD) {
        float mu = bnstat[j] / (float)NN;
        float var = bnstat[CD + j] / (float)NN - mu * mu;
        float inv = rsqrtf(var + 1e-5f);
        float s = gamma[j] * inv;
        sc[j] = s;
        sc[CD + j] = beta[j] - mu * s;
    }
}

// ---------------- prep2 ----------------
__global__ __launch_bounds__(256) void k_prep2(
    const float* __restrict__ x1pre, const float* __restrict__ sc,
    const float* __restrict__ nn2w1, float* __restrict__ x1W) {
    int i = blockIdx.x * 256 + threadIdx.x;
    if (i >= NN) return;
    const float4* xr = reinterpret_cast<const float4*>(x1pre + (size_t)i * CD);
    float4 v0 = xr[0], v1 = xr[1];
    float xn[CD];
    xn[0] = v0.x * sc[0] + sc[8];  xn[1] = v0.y * sc[1] + sc[9];
    xn[2] = v0.z * sc[2] + sc[10]; xn[3] = v0.w * sc[3] + sc[11];
    xn[4] = v1.x * sc[4] + sc[12]; xn[5] = v1.y * sc[5] + sc[13];
    xn[6] = v1.z * sc[6] + sc[14]; xn[7] = v1.w * sc[7] + sc[15];
    float xw[24];
#pragma unroll
    for (int j = 0; j < 24; ++j) xw[j] = 0.f;
#pragma unroll
    for (int k = 0; k < CD; ++k)
#pragma unroll
        for (int j = 0; j < 24; ++j) xw[j] += xn[k] * nn2w1[k * 24 + j];
    float4* xo = reinterpret_cast<float4*>(x1W + (size_t)i * 24);
#pragma unroll
    for (int q = 0; q < 6; ++q)
        xo[q] = make_float4(xw[4 * q], xw[4 * q + 1], xw[4 * q + 2], xw[4 * q + 3]);
}

// ---------------- conv2 messages (bigws): split A(8)/B(2) layout for wide agg ----------------
__global__ __launch_bounds__(256, 4) void k_conv2mr(
    const float* __restrict__ eaS, const int* __restrict__ ps2,
    const float* __restrict__ x1W,
    const float* __restrict__ w1, const float* __restrict__ b1,
    const float* __restrict__ w2, const float* __restrict__ b2,
    const float* __restrict__ w3, const float* __restrict__ b3,
    float* __restrict__ msgsA, float* __restrict__ msgsB) {
    constexpr int M = CD + D;  // 24
    int t = blockIdx.x * 256 + threadIdx.x;
    if (t >= NE) return;
    int src = ps2[t];
    float ea[D];
    const float4* eg = reinterpret_cast<const float4*>(eaS + (size_t)t * 16);
#pragma unroll
    for (int q = 0; q < 4; ++q) {
        float4 v = eg[q];
        ea[4 * q] = v.x; ea[4 * q + 1] = v.y; ea[4 * q + 2] = v.z; ea[4 * q + 3] = v.w;
    }
    float a[M];
    const float4* xg = reinterpret_cast<const float4*>(x1W + (size_t)src * 24);
#pragma unroll
    for (int q = 0; q < 6; ++q) {
        float4 v = xg[q];
        a[4 * q] = v.x; a[4 * q + 1] = v.y; a[4 * q + 2] = v.z; a[4 * q + 3] = v.w;
    }
#pragma unroll
    for (int j = 0; j < M; ++j) a[j] += b1[j];
#pragma unroll
    for (int k = 0; k < D; ++k)
#pragma unroll
        for (int j = 0; j < M; ++j) a[j] += ea[k] * w1[(CD + k) * M + j];
#pragma unroll
    for (int j = 0; j < M; ++j) a[j] = leaky(a[j]);
    float bv[M];
#pragma unroll
    for (int j = 0; j < M; ++j) bv[j] = b2[j];
#pragma unroll
    for (int k = 0; k < M; ++k)
#pragma unroll
        for (int j = 0; j < M; ++j) bv[j] += a[k] * w2[k * M + j];
#pragma unroll
    for (int j = 0; j < M; ++j) bv[j] = leaky(bv[j]);
    float o[C];
#pragma unroll
    for (int j = 0; j < C; ++j) o[j] = b3[j];
#pragma unroll
    for (int k = 0; k < M; ++k)
#pragma unroll
        for (int j = 0; j < C; ++j) o[j] += bv[k] * w3[k * C + j];
    float4* ma = reinterpret_cast<float4*>(msgsA + (size_t)t * CD);
    ma[0] = make_float4(o[0], o[1], o[2], o[3]);
    ma[1] = make_float4(o[4], o[5], o[6], o[7]);
    *reinterpret_cast<float2*>(msgsB + (size_t)t * 2) = make_float2(o[8], o[9]);
}

// ---------------- conv2 messages (mid fallback, stride-10 msgs) ----------------
__global__ __launch_bounds__(256) void k_conv2m(
    const float* __restrict__ earaw, const int* __restrict__ pe2, const int* __restrict__ ps2,
    const float* __restrict__ x1W,
    const float* __restrict__ ew1, const float* __restrict__ eb1,
    const float* __restrict__ ew2, const float* __restrict__ eb2,
    const float* __restrict__ w1, const float* __restrict__ b1,
    const float* __restrict__ w2, const float* __restrict__ b2,
    const float* __restrict__ w3, const float* __restrict__ b3,
    float* __restrict__ msgs) {
    constexpr int M = CD + D;  // 24
    int t = blockIdx.x * 256 + threadIdx.x;
    if (t >= NE) return;
    int e = pe2[t], src = ps2[t];
    float ea[D];
    edge_encode(earaw, e, ew1, eb1, ew2, eb2, ea);
    float a[M];
    const float4* xg = reinterpret_cast<const float4*>(x1W + (size_t)src * 24);
#pragma unroll
    for (int q = 0; q < 6; ++q) {
        float4 v = xg[q];
        a[4 * q] = v.x; a[4 * q + 1] = v.y; a[4 * q + 2] = v.z; a[4 * q + 3] = v.w;
    }
#pragma unroll
    for (int j = 0; j < M; ++j) a[j] += b1[j];
#pragma unroll
    for (int k = 0; k < D; ++k)
#pragma unroll
        for (int j = 0; j < M; ++j) a[j] += ea[k] * w1[(CD + k) * M + j];
#pragma unroll
    for (int j = 0; j < M; ++j) a[j] = leaky(a[j]);
    float bv[M];
#pragma unroll
    for (int j = 0; j < M; ++j) bv[j] = b2[j];
#pragma unroll
    for (int k = 0; k < M; ++k)
#pragma unroll
        for (int j = 0; j < M; ++j) bv[j] += a[k] * w2[k * M + j];
#pragma unroll
    for (int j = 0; j < M; ++j) bv[j] = leaky(bv[j]);
    float o[C];
#pragma unroll
    for (int j = 0; j < C; ++j) o[j] = b3[j];
#pragma unroll
    for (int k = 0; k < M; ++k)
#pragma unroll
        for (int j = 0; j < C; ++j) o[j] += bv[k] * w3[k * C + j];
    float2* mp = reinterpret_cast<float2*>(msgs + (size_t)t * C);
#pragma unroll
    for (int q = 0; q < 5; ++q) mp[q] = make_float2(o[2 * q], o[2 * q + 1]);
}

// ---------------- agg2 wide: 16 lanes per node over split A/B msgs ----------------
__global__ __launch_bounds__(256) void k_agg2w(
    const float* __restrict__ msgsA, const float* __restrict__ msgsB,
    const unsigned* __restrict__ nptr, float* __restrict__ agg2) {
    int tid = blockIdx.x * 256 + threadIdx.x;
    int i = tid >> 4;
    int l = tid & 15;
    if (i >= NN) return;
    unsigned p0 = nptr[i], p1 = nptr[i + 1];
    int q = l & 1, roff = l >> 1;
    float4 acc = make_float4(0.f, 0.f, 0.f, 0.f);
    float2 accB = make_float2(0.f, 0.f);
    for (unsigned r = p0 + roff; r < p1; r += 8) {
        float4 m = *reinterpret_cast<const float4*>(msgsA + (size_t)r * CD + q * 4);
        acc.x += m.x; acc.y += m.y; acc.z += m.z; acc.w += m.w;
        if (q == 0) {
            float2 b = *reinterpret_cast<const float2*>(msgsB + (size_t)r * 2);
            accB.x += b.x; accB.y += b.y;
        }
    }
#pragma unroll
    for (int off = 2; off <= 8; off <<= 1) {
        acc.x += __shfl_down(acc.x, off);
        acc.y += __shfl_down(acc.y, off);
        acc.z += __shfl_down(acc.z, off);
        acc.w += __shfl_down(acc.w, off);
        accB.x += __shfl_down(accB.x, off);
        accB.y += __shfl_down(accB.y, off);
    }
    if (l == 0) {
        *reinterpret_cast<float4*>(agg2 + (size_t)i * 12) = acc;
        *reinterpret_cast<float2*>(agg2 + (size_t)i * 12 + 8) = accB;
    } else if (l == 1) {
        *reinterpret_cast<float4*>(agg2 + (size_t)i * 12 + 4) = acc;
    }
}

// ---------------- final epilogue: 1 thread/node ----------------
__global__ __launch_bounds__(256) void k_final_epi(
    const float* __restrict__ x1pre, const float* __restrict__ sc,
    const float* __restrict__ agg2,
    const float* __restrict__ root2, const float* __restrict__ bias2,
    const float* __restrict__ fcw, const float* __restrict__ fcb,
    float* __restrict__ out) {
    int i = blockIdx.x * 256 + threadIdx.x;
    if (i >= NN) return;
    float z[CD + C];
    const float4* xr = reinterpret_cast<const float4*>(x1pre + (size_t)i * CD);
    float4 v0 = xr[0], v1 = xr[1];
    z[0] = v0.x; z[1] = v0.y; z[2] = v0.z; z[3] = v0.w;
    z[4] = v1.x; z[5] = v1.y; z[6] = v1.z; z[7] = v1.w;
#pragma unroll
    for (int j = 0; j < CD; ++j) z[j] = z[j] * sc[j] + sc[CD + j];
    float x2[C];
    {
        const float4* ag = reinterpret_cast<const float4*>(agg2 + (size_t)i * 12);
        float4 a0 = ag[0], a1 = ag[1];
        float2 a2 = *reinterpret_cast<const float2*>(agg2 + (size_t)i * 12 + 8);
        x2[0] = bias2[0] + a0.x; x2[1] = bias2[1] + a0.y;
        x2[2] = bias2[2] + a0.z; x2[3] = bias2[3] + a0.w;
        x2[4] = bias2[4] + a1.x; x2[5] = bias2[5] + a1.y;
        x2[6] = bias2[6] + a1.z; x2[7] = bias2[7] + a1.w;
        x2[8] = bias2[8] + a2.x; x2[9] = bias2[9] + a2.y;
    }
#pragma unroll
    for (int k = 0; k < CD; ++k)
#pragma unroll
        for (int j = 0; j < C; ++j) x2[j] += z[k] * root2[k * C + j];
#pragma unroll
    for (int j = 0; j < C; ++j) z[CD + j] = fmaxf(x2[j], 0.f);
    float lg[C];
#pragma unroll
    for (int j = 0; j < C; ++j) lg[j] = fcb[j];
#pragma unroll
    for (int k = 0; k < CD + C; ++k)
#pragma unroll
        for (int j = 0; j < C; ++j) lg[j] += z[k] * fcw[k * C + j];
    float mx = lg[0];
#pragma unroll
    for (int j = 1; j < C; ++j) mx = fmaxf(mx, lg[j]);
    float se = 0.f;
#pragma unroll
    for (int j = 0; j < C; ++j) se += __expf(lg[j] - mx);
    float ls = __logf(se) + mx;
    float* op = out + (size_t)i * C;
#pragma unroll
    for (int j = 0; j < C; ++j) op[j] = lg[j] - ls;
}

// ---------------- final (mid fallback): 1 thread/node segmented sum over stride-10 msgs ----------------
__global__ __launch_bounds__(256) void k_finalm2(
    const float* __restrict__ x1pre, const float* __restrict__ sc,
    const float* __restrict__ msgs, const unsigned* __restrict__ nptr,
    const float* __restrict__ root2, const float* __restrict__ bias2,
    const float* __restrict__ fcw, const float* __restrict__ fcb,
    float* __restrict__ out) {
    int i = blockIdx.x * 256 + threadIdx.x;
    if (i >= NN) return;
    float z[CD + C];
    const float4* xr = reinterpret_cast<const float4*>(x1pre + (size_t)i * CD);
    float4 v0 = xr[0], v1 = xr[1];
    z[0] = v0.x; z[1] = v0.y; z[2] = v0.z; z[3] = v0.w;
    z[4] = v1.x; z[5] = v1.y; z[6] = v1.z; z[7] = v1.w;
#pragma unroll
    for (int j = 0; j < CD; ++j) z[j] = z[j] * sc[j] + sc[CD + j];
    float x2[C];
#pragma unroll
    for (int j = 0; j < C; ++j) x2[j] = bias2[j];
    unsigned p0 = nptr[i], p1 = nptr[i + 1];
#pragma unroll 4
    for (unsigned p = p0; p < p1; ++p) {
        const float2* mp = reinterpret_cast<const float2*>(msgs + (size_t)p * C);
#pragma unroll
        for (int q = 0; q < 5; ++q) {
            float2 m = mp[q];
            x2[2 * q] += m.x; x2[2 * q + 1] += m.y;
        }
    }
#pragma unroll
    for (int k = 0; k < CD; ++k)
#pragma unroll
        for (int j = 0; j < C; ++j) x2[j] += z[k] * root2[k * C + j];
#pragma unroll
    for (int j = 0; j < C; ++j) z[CD + j] = fmaxf(x2[j], 0.f);
    float lg[C];
#pragma unroll
    for (int j = 0; j < C; ++j) lg[j] = fcb[j];
#pragma unroll
    for (int k = 0; k < CD + C; ++k)
#pragma unroll
        for (int j = 0; j < C; ++j) lg[j] += z[k] * fcw[k * C + j];
    float mx = lg[0];
#pragma unroll
    for (int j = 1; j < C; ++j) mx = fmaxf(mx, lg[j]);
    float se = 0.f;
#pragma unroll
    for (int j = 0; j < C; ++j) se += __expf(lg[j] - mx);
    float ls = __logf(se) + mx;
    float* op = out + (size_t)i * C;
#pragma unroll
    for (int j = 0; j < C; ++j) op[j] = lg[j] - ls;
}

// ================= atomic fallback kernels =================
__global__ __launch_bounds__(256) void k_conv1(
    const float* __restrict__ earaw, const int* __restrict__ ei, const float* __restrict__ h,
    const float* __restrict__ ew1, const float* __restrict__ eb1,
    const float* __restrict__ ew2, const float* __restrict__ eb2,
    const float* __restrict__ w1, const float* __restrict__ b1,
    const float* __restrict__ w2, const float* __restrict__ b2,
    const float* __restrict__ w3, const float* __restrict__ b3,
    float* __restrict__ agg) {
    int e = blockIdx.x * 256 + threadIdx.x;
    if (e >= NE) return;
    int src = ei[e], dst = ei[NE + e];
    float a[32];
    edge_encode(earaw, e, ew1, eb1, ew2, eb2, a + D);
    const float4* hr = reinterpret_cast<const float4*>(h + (size_t)src * D);
#pragma unroll
    for (int q = 0; q < 4; ++q) {
        float4 v = hr[q];
        a[4 * q] = v.x; a[4 * q + 1] = v.y; a[4 * q + 2] = v.z; a[4 * q + 3] = v.w;
    }
    float o[CD];
    mlp1(a, w1, b1, w2, b2, w3, b3, o);
    float* ap = agg + (size_t)dst * CD;
#pragma unroll
    for (int j = 0; j < CD; ++j) atomicAdd(ap + j, o[j]);
}

__global__ __launch_bounds__(256) void k_conv2(
    const float* __restrict__ earaw, const int* __restrict__ ei,
    const float* __restrict__ x1pre, const float* __restrict__ sc,
    const float* __restrict__ ew1, const float* __restrict__ eb1,
    const float* __restrict__ ew2, const float* __restrict__ eb2,
    const float* __restrict__ w1, const float* __restrict__ b1,
    const float* __restrict__ w2, const float* __restrict__ b2,
    const float* __restrict__ w3, const float* __restrict__ b3,
    float* __restrict__ agg2) {
    int e = blockIdx.x * 256 + threadIdx.x;
    if (e >= NE) return;
    int src = ei[e], dst = ei[NE + e];
    float a[CD + D];
    edge_encode(earaw, e, ew1, eb1, ew2, eb2, a + CD);
    const float4* xr = reinterpret_cast<const float4*>(x1pre + (size_t)src * CD);
    float4 v0 = xr[0], v1 = xr[1];
    a[0] = v0.x * sc[0] + sc[8];  a[1] = v0.y * sc[1] + sc[9];
    a[2] = v0.z * sc[2] + sc[10]; a[3] = v0.w * sc[3] + sc[11];
    a[4] = v1.x * sc[4] + sc[12]; a[5] = v1.y * sc[5] + sc[13];
    a[6] = v1.z * sc[6] + sc[14]; a[7] = v1.w * sc[7] + sc[15];
    float o[C];
    mlp2(a, w1, b1, w2, b2, w3, b3, o);
    float* ap = agg2 + (size_t)dst * C;
#pragma unroll
    for (int j = 0; j < C; ++j) atomicAdd(ap + j, o[j]);
}

__global__ __launch_bounds__(256) void k_node1(
    const float* __restrict__ agg, const float* __restrict__ h,
    const float* __restrict__ root1, const float* __restrict__ bias1,
    float* __restrict__ x1pre, float* __restrict__ bnstat) {
    int i = blockIdx.x * 256 + threadIdx.x;
    float v[CD], sq[CD];
    if (i < NN) {
        float hv[D];
        const float4* hr = reinterpret_cast<const float4*>(h + (size_t)i * D);
#pragma unroll
        for (int q = 0; q < 4; ++q) {
            float4 w = hr[q];
            hv[4 * q] = w.x; hv[4 * q + 1] = w.y; hv[4 * q + 2] = w.z; hv[4 * q + 3] = w.w;
        }
#pragma unroll
        for (int j = 0; j < CD; ++j) v[j] = bias1[j] + agg[(size_t)i * CD + j];
#pragma unroll
        for (int k = 0; k < D; ++k)
#pragma unroll
            for (int j = 0; j < CD; ++j) v[j] += hv[k] * root1[k * CD + j];
#pragma unroll
        for (int j = 0; j < CD; ++j) v[j] = fmaxf(v[j], 0.f);
#pragma unroll
        for (int j = 0; j < CD; ++j) x1pre[(size_t)i * CD + j] = v[j];
    } else {
#pragma unroll
        for (int j = 0; j < CD; ++j) v[j] = 0.f;
    }
#pragma unroll
    for (int j = 0; j < CD; ++j) sq[j] = v[j] * v[j];
#pragma unroll
    for (int off = 32; off > 0; off >>= 1) {
#pragma unroll
        for (int j = 0; j < CD; ++j) {
            v[j] += __shfl_down(v[j], off);
            sq[j] += __shfl_down(sq[j], off);
        }
    }
    if ((threadIdx.x & 63) == 0) {
#pragma unroll
        for (int j = 0; j < CD; ++j) {
            atomicAdd(&bnstat[j], v[j]);
            atomicAdd(&bnstat[CD + j], sq[j]);
        }
    }
}

__global__ __launch_bounds__(256) void k_final(
    const float* __restrict__ x1pre, const float* __restrict__ sc,
    const float* __restrict__ agg2, const float* __restrict__ root2,
    const float* __restrict__ bias2, const float* __restrict__ fcw,
    const float* __restrict__ fcb, float* __restrict__ out) {
    int i = blockIdx.x * 256 + threadIdx.x;
    if (i >= NN) return;
    float z[CD + C];
    const float4* xr = reinterpret_cast<const float4*>(x1pre + (size_t)i * CD);
    float4 v0 = xr[0], v1 = xr[1];
    z[0] = v0.x; z[1] = v0.y; z[2] = v0.z; z[3] = v0.w;
    z[4] = v1.x; z[5] = v1.y; z[6] = v1.z; z[7] = v1.w;
#pragma unroll
    for (int j = 0; j < CD; ++j) z[j] = z[j] * sc[j] + sc[CD + j];
    float x2[C];
#pragma unroll
    for (int j = 0; j < C; ++j) x2[j] = bias2[j] + agg2[(size_t)i * C + j];
#pragma unroll
    for (int k = 0; k < CD; ++k)
#pragma unroll
        for (int j = 0; j < C; ++j) x2[j] += z[k] * root2[k * C + j];
#pragma unroll
    for (int j = 0; j < C; ++j) z[CD + j] = fmaxf(x2[j], 0.f);
    float lg[C];
#pragma unroll
    for (int j = 0; j < C; ++j) lg[j] = fcb[j];
#pragma unroll
    for (int k = 0; k < CD + C; ++k)
#pragma unroll
        for (int j = 0; j < C; ++j) lg[j] += z[k] * fcw[k * C + j];
    float mx = lg[0];
#pragma unroll
    for (int j = 1; j < C; ++j) mx = fmaxf(mx, lg[j]);
    float se = 0.f;
#pragma unroll
    for (int j = 0; j < C; ++j) se += __expf(lg[j] - mx);
    float ls = __logf(se) + mx;
    float* op = out + (size_t)i * C;
#pragma unroll
    for (int j = 0; j < C; ++j) op[j] = lg[j] - ls;
}

extern "C" void kernel_launch(void* const* d_in, const int* in_sizes, int n_in,
                              void* d_out, int out_size, void* d_ws, size_t ws_size,
                              hipStream_t stream) {
    const float* x      = (const float*)d_in[0];
    const float* earaw  = (const float*)d_in[1];
    const float* twin   = (const float*)d_in[2];
    const int*   ei     = (const int*)d_in[3];
    const float* ne_w1  = (const float*)d_in[4];
    const float* ne_b1  = (const float*)d_in[5];
    const float* ne_w2  = (const float*)d_in[6];
    const float* ne_b2  = (const float*)d_in[7];
    const float* ee_w1  = (const float*)d_in[8];
    const float* ee_b1  = (const float*)d_in[9];
    const float* ee_w2  = (const float*)d_in[10];
    const float* ee_b2  = (const float*)d_in[11];
    const float* tw_w   = (const float*)d_in[12];
    const float* tw_b   = (const float*)d_in[13];
    const float* nn1_w1 = (const float*)d_in[14];
    const float* nn1_b1 = (const float*)d_in[15];
    const float* nn1_w2 = (const float*)d_in[16];
    const float* nn1_b2 = (const float*)d_in[17];
    const float* nn1_w3 = (const float*)d_in[18];
    const float* nn1_b3 = (const float*)d_in[19];
    const float* root1  = (const float*)d_in[20];
    const float* bias1  = (const float*)d_in[21];
    const float* bn_g   = (const float*)d_in[22];
    const float* bn_b   = (const float*)d_in[23];
    const float* nn2_w1 = (const float*)d_in[24];
    const float* nn2_b1 = (const float*)d_in[25];
    const float* nn2_w2 = (const float*)d_in[26];
    const float* nn2_b2 = (const float*)d_in[27];
    const float* nn2_w3 = (const float*)d_in[28];
    const float* nn2_b3 = (const float*)d_in[29];
    const float* root2  = (const float*)d_in[30];
    const float* bias2  = (const float*)d_in[31];
    const float* fc_w   = (const float*)d_in[32];
    const float* fc_b   = (const float*)d_in[33];
    float* out = (float*)d_out;
    float* ws = (float*)d_ws;

    // ---------- sorted-path layout (floats) ----------
    const size_t f_hW1    = 0;            // NN*32
    const size_t f_hroot  = 3200000;      // NN*8
    const size_t f_x1pre  = 4000000;      // NN*8
    const size_t f_x1W    = 4800000;      // NN*24
    const size_t f_bn     = 7200000;      // 32
    const size_t f_total  = 7200032;      // 256
    const size_t f_bstart = 7200288;      // 320
    const size_t f_histp  = 7200608;      // 65536 (dead after scanA; bnpart overlays: 391*16)
    const size_t f_offp   = 7266144;      // 65536
    const size_t f_nptr   = 7331680;      // 100352
    const size_t f_pe     = 7432032;      // NE (dead after sort2; agg2 overlays: NN*12)
    const size_t f_ps     = 9032032;      // NE
    const size_t f_pd     = 10632032;     // NE
    const size_t f_pe2    = 12232032;     // NE
    const size_t f_ps2    = 13832032;     // NE
    const size_t f_msgs   = 15432032;     // NE*10 (conv1: NE*8; conv2: A=NE*8 + B=NE*2)
    const size_t f_endB   = 31432032;     // mid path end
    const size_t f_eaS    = 31432032;     // NE*16
    const size_t f_endA   = 57032032;     // +eaS

    if (ws_size >= f_endB * sizeof(float)) {
        float* hW1    = ws + f_hW1;
        float* hroot  = ws + f_hroot;
        float* x1pre  = ws + f_x1pre;
        float* x1W    = ws + f_x1W;
        float* bnstat = ws + f_bn;
        float* sc     = ws + f_bn + 16;
        unsigned* total  = (unsigned*)(ws + f_total);
        unsigned* bstart = (unsigned*)(ws + f_bstart);
        unsigned* histp  = (unsigned*)(ws + f_histp);
        unsigned* offp   = (unsigned*)(ws + f_offp);
        unsigned* nptr   = (unsigned*)(ws + f_nptr);
        int* pe  = (int*)(ws + f_pe);
        int* ps  = (int*)(ws + f_ps);
        int* pd  = (int*)(ws + f_pd);
        int* pe2 = (int*)(ws + f_pe2);
        int* ps2 = (int*)(ws + f_ps2);
        float* msgs  = ws + f_msgs;             // conv1 msgs, stride 8
        float* msgsB = ws + f_msgs + (size_t)NE * 8;  // conv2 cols 8-9, stride 2
        float* agg2  = ws + f_pe;               // NN*12, overlays dead pe
        float* bnpart = ws + f_histp;           // 391*16, overlays dead histp
        float* eaS   = ws + f_eaS;
        bool bigws = ws_size >= f_endA * sizeof(float);

        k_node_enc2<<<(NN + 255) / 256, 256, 0, stream>>>(
            x, twin, ne_w1, ne_b1, ne_w2, ne_b2, tw_w, tw_b, nn1_w1, root1, hW1, hroot);
        k_hist<<<NBLK, 256, 0, stream>>>(ei, histp);
        k_scanA<<<NB, 256, 0, stream>>>(histp, offp, total);
        k_scanB<<<1, 256, 0, stream>>>(total, bstart, bnstat);
        k_scatter<<<NBLK, 256, 0, stream>>>(ei, offp, bstart, pe, ps, pd);
        k_sort2<<<NB, 256, 0, stream>>>(pe, ps, pd, bstart, pe2, ps2, nptr);
        if (bigws) {
            k_conv1mw<<<(NE + 255) / 256, 256, 0, stream>>>(
                earaw, pe2, ps2, hW1, ee_w1, ee_b1, ee_w2, ee_b2,
                nn1_w1, nn1_b1, nn1_w2, nn1_b2, nn1_w3, nn1_b3, msgs, eaS);
        } else {
            k_conv1m<<<(NE + 255) / 256, 256, 0, stream>>>(
                earaw, pe2, ps2, hW1, ee_w1, ee_b1, ee_w2, ee_b2,
                nn1_w1, nn1_b1, nn1_w2, nn1_b2, nn1_w3, nn1_b3, msgs);
        }
        k_agg1w<<<AGG_BLOCKS, 256, 0, stream>>>(msgs, nptr, hroot, bias1, x1pre);
        k_bnstat2<<<BN_BLOCKS, 256, 0, stream>>>(x1pre, bnpart);
        k_bnfin2<<<1, 64, 0, stream>>>(bnpart, bn_g, bn_b, sc);
        k_prep2<<<(NN + 255) / 256, 256, 0, stream>>>(x1pre, sc, nn2_w1, x1W);
        if (bigws) {
            k_conv2mr<<<(NE + 255) / 256, 256, 0, stream>>>(
                eaS, ps2, x1W,
                nn2_w1, nn2_b1, nn2_w2, nn2_b2, nn2_w3, nn2_b3, msgs, msgsB);
            k_agg2w<<<AGG_BLOCKS, 256, 0, stream>>>(msgs, msgsB, nptr, agg2);
            k_final_epi<<<(NN + 255) / 256, 256, 0, stream>>>(
                x1pre, sc, agg2, root2, bias2, fc_w, fc_b, out);
        } else {
            k_conv2m<<<(NE + 255) / 256, 256, 0, stream>>>(
                earaw, pe2, ps2, x1W, ee_w1, ee_b1, ee_w2, ee_b2,
                nn2_w1, nn2_b1, nn2_w2, nn2_b2, nn2_w3, nn2_b3, msgs);
            k_finalm2<<<(NN + 255) / 256, 256, 0, stream>>>(
                x1pre, sc, msgs, nptr, root2, bias2, fc_w, fc_b, out);
        }
    } else {
        // fallback: atomic path
        float* h     = ws;
        float* x1pre = ws + (size_t)NN * 16;
        float* agg   = ws + (size_t)NN * 24;
        float* agg2  = ws + (size_t)NN * 32;
        float* bnst  = ws + (size_t)NN * 42;
        float* scf   = bnst + 16;
        int zn = NN * 18 + 16;
        k_zero<<<(zn + 255) / 256, 256, 0, stream>>>(agg, zn);
        k_node_enc<<<(NN + 255) / 256, 256, 0, stream>>>(
            x, twin, ne_w1, ne_b1, ne_w2, ne_b2, tw_w, tw_b, h);
        k_conv1<<<(NE + 255) / 256, 256, 0, stream>>>(
            earaw, ei, h, ee_w1, ee_b1, ee_w2, ee_b2,
            nn1_w1, nn1_b1, nn1_w2, nn1_b2, nn1_w3, nn1_b3, agg);
        k_node1<<<(NN + 255) / 256, 256, 0, stream>>>(
            agg, h, root1, bias1, x1pre, bnst);
        k_bnfin<<<1, 64, 0, stream>>>(bnst, bn_g, bn_b, scf);
        k_conv2<<<(NE + 255) / 256, 256, 0, stream>>>(
            earaw, ei, x1pre, scf, ee_w1, ee_b1, ee_w2, ee_b2,
            nn2_w1, nn2_b1, nn2_w2, nn2_b2, nn2_w3, nn2_b3, agg2);
        k_final<<<(NN + 255) / 256, 256, 0, stream>>>(
            x1pre, scf, agg2, root2, bias2, fc_w, fc_b, out);
    }
}